// Round 1
// baseline (253.651 us; speedup 1.0000x reference)
//
#include <hip/hip_runtime.h>
#include <hip/hip_bf16.h>
#include <math.h>

#define B_ 2
#define H_ 128
#define W_ 128
#define C_ 256
#define HID 64
#define PIX_PER (H_*W_)          // 16384
#define NPIX (B_*PIX_PER)        // 32768
#define KPAD 800                 // 780 padded to 800 (25 * 32)
#define K1STEPS 25
#define K3STEPS 18               // 576 / 32

using f32x4 = __attribute__((ext_vector_type(4))) float;
using s16x8 = __attribute__((ext_vector_type(8))) short;
using u16x4 = __attribute__((ext_vector_type(4))) unsigned short;
using u16x8 = __attribute__((ext_vector_type(8))) unsigned short;

__device__ __forceinline__ float bf2f(unsigned short u) {
    return __uint_as_float(((unsigned)u) << 16);
}
__device__ __forceinline__ unsigned short f2bf(float f) {
    unsigned u = __float_as_uint(f);
    u += 0x7FFFu + ((u >> 16) & 1u);
    return (unsigned short)(u >> 16);
}
__device__ __forceinline__ float clean15(float v) {
    if (v != v) v = 0.f;
    return fminf(fmaxf(v, -1.5f), 1.5f);
}
__device__ __forceinline__ float clean01(float v) {
    if (v != v) v = 0.f;
    return fminf(fmaxf(v, 0.f), 1.f);
}

// ---------------- transpose NCHW -> NHWC bf16 with nan cleanup ----------------
__global__ __launch_bounds__(256) void k_transpose(const float* __restrict__ A,
                                                   const float* __restrict__ Bm,
                                                   unsigned short* __restrict__ faT,
                                                   unsigned short* __restrict__ fbT)
{
    __shared__ float tile[32][33];
    int hw0 = blockIdx.x * 32;
    int c0  = blockIdx.y * 32;
    int z   = blockIdx.z;            // b*2 + which
    int b   = z >> 1;
    const float* src = (z & 1) ? Bm : A;
    unsigned short* dst = (z & 1) ? fbT : faT;
    int tx = threadIdx.x & 31, ty = threadIdx.x >> 5;   // 32 x 8
    const float* s = src + ((size_t)b * C_ + c0) * (size_t)PIX_PER + hw0;
#pragma unroll
    for (int i = 0; i < 32; i += 8) {
        float v = s[(size_t)(ty + i) * PIX_PER + tx];
        if (!isfinite(v)) v = 0.f;
        tile[ty + i][tx] = v;
    }
    __syncthreads();
    unsigned short* d = dst + ((size_t)b * PIX_PER + hw0) * C_ + c0;
#pragma unroll
    for (int i = 0; i < 32; i += 8)
        d[(size_t)(ty + i) * C_ + tx] = f2bf(tile[tx][ty + i]);
}

// ---------------- weight packing into MFMA B-fragment order ----------------
// B-frag (16x16x32): lane l, elem j holds B[k][n], n = l&15, k = 8*(l>>4)+j
// layout: pack[((ks*4 + nt)*64 + lane)*8 + j]
__global__ __launch_bounds__(256) void k_pack(const float* __restrict__ w1,
                                              const float* __restrict__ w2,
                                              const float* __restrict__ w3,
                                              unsigned short* __restrict__ p1,
                                              unsigned short* __restrict__ p2,
                                              unsigned short* __restrict__ p3)
{
    int t = blockIdx.x * 256 + threadIdx.x;
    if (t < 6400) {                                   // enc1: 25 ksteps
        int lane = t & 63, nt = (t >> 6) & 3, ks = t >> 8;
        int n = nt * 16 + (lane & 15);
        int kb = ks * 32 + 8 * (lane >> 4);
#pragma unroll
        for (int j = 0; j < 8; j++) {
            int k = kb + j;
            p1[(size_t)t * 8 + j] = (k < 780) ? f2bf(w1[(size_t)n * 780 + k]) : (unsigned short)0;
        }
    } else if (t < 6400 + 2 * 4608) {                 // enc2/enc3: 18 ksteps each
        int which = (t - 6400) / 4608;
        int idx = (t - 6400) % 4608;
        const float* w = which ? w3 : w2;
        unsigned short* p = which ? p3 : p2;
        int lane = idx & 63, nt = (idx >> 6) & 3, ks = idx >> 8;
        int n = nt * 16 + (lane & 15);
        int tap = ks >> 1;
        int ky = tap / 3, kx = tap % 3;
#pragma unroll
        for (int j = 0; j < 8; j++) {
            int c = (ks & 1) * 32 + 8 * (lane >> 4) + j;
            p[(size_t)idx * 8 + j] = f2bf(w[(((size_t)n * 64 + c) * 3 + ky) * 3 + kx]);
        }
    }
}

// ---------------- sampling + correlation + x assembly (1 wave / pixel) ----------------
__global__ __launch_bounds__(256) void k_sample(const float* __restrict__ cw,
                                                const float* __restrict__ confp,
                                                const unsigned short* __restrict__ faT,
                                                const unsigned short* __restrict__ fbT,
                                                unsigned short* __restrict__ xbuf)
{
    int wid = (blockIdx.x * 256 + threadIdx.x) >> 6;   // pixel id
    int lane = threadIdx.x & 63;
    if (wid >= NPIX) return;
    int b = wid >> 14, y = (wid >> 7) & 127, x = wid & 127;

    float gx = clean15(cw[(size_t)wid * 2 + 0]);
    float gy = clean15(cw[(size_t)wid * 2 + 1]);
    float conf = clean01(confp[wid]);

    // fa: 4 channels per lane
    u16x4 fau = *(const u16x4*)(faT + (size_t)wid * C_ + lane * 4);
    float fa[4];
#pragma unroll
    for (int i = 0; i < 4; i++) fa[i] = bf2f(fau[i]);
    float fa2 = fa[0]*fa[0] + fa[1]*fa[1] + fa[2]*fa[2] + fa[3]*fa[3];

    float dotv[9], s2v[9], wb[4];
    const unsigned short* fbB = fbT + (size_t)b * PIX_PER * C_ + lane * 4;
#pragma unroll
    for (int j = 0; j < 9; j++) {
        int dy = j / 3 - 1, dx = j % 3 - 1;
        float gxj = fminf(fmaxf(gx + (float)dx * 0.015625f, -1.5f), 1.5f);
        float gyj = fminf(fmaxf(gy + (float)dy * 0.015625f, -1.5f), 1.5f);
        float pxf = fminf(fmaxf((gxj + 1.f) * 64.f - 0.5f, 0.f), 127.f);
        float pyf = fminf(fmaxf((gyj + 1.f) * 64.f - 0.5f, 0.f), 127.f);
        float x0f = floorf(pxf), y0f = floorf(pyf);
        float wx = pxf - x0f, wy = pyf - y0f;
        int x0 = (int)x0f, y0 = (int)y0f;
        int x1 = min(x0 + 1, 127), y1 = min(y0 + 1, 127);
        u16x4 a00 = *(const u16x4*)(fbB + ((size_t)y0 * 128 + x0) * C_);
        u16x4 a01 = *(const u16x4*)(fbB + ((size_t)y0 * 128 + x1) * C_);
        u16x4 a10 = *(const u16x4*)(fbB + ((size_t)y1 * 128 + x0) * C_);
        u16x4 a11 = *(const u16x4*)(fbB + ((size_t)y1 * 128 + x1) * C_);
        float w00 = (1.f - wx) * (1.f - wy), w01 = wx * (1.f - wy);
        float w10 = (1.f - wx) * wy,         w11 = wx * wy;
        float d = 0.f, s2 = 0.f;
#pragma unroll
        for (int i = 0; i < 4; i++) {
            float sv = bf2f(a00[i]) * w00 + bf2f(a01[i]) * w01 +
                       bf2f(a10[i]) * w10 + bf2f(a11[i]) * w11;
            if (j == 4) wb[i] = sv;
            d  += fa[i] * sv;
            s2 += sv * sv;
        }
        dotv[j] = d; s2v[j] = s2;
    }

    // wave reductions (width 64)
#pragma unroll
    for (int m = 32; m > 0; m >>= 1) {
        fa2 += __shfl_xor(fa2, m);
#pragma unroll
        for (int j = 0; j < 9; j++) {
            dotv[j] += __shfl_xor(dotv[j], m);
            s2v[j]  += __shfl_xor(s2v[j], m);
        }
    }
    float inv_na = 1.f / fmaxf(sqrtf(fa2), 1e-12f);

    unsigned short* xr = xbuf + (size_t)wid * KPAD;
    u16x4 o;
#pragma unroll
    for (int i = 0; i < 4; i++) o[i] = f2bf(fa[i]);
    *(u16x4*)(xr + lane * 4) = o;
#pragma unroll
    for (int i = 0; i < 4; i++) o[i] = f2bf(wb[i]);
    *(u16x4*)(xr + 256 + lane * 4) = o;
#pragma unroll
    for (int i = 0; i < 4; i++) o[i] = f2bf(fabsf(fa[i] - wb[i]));
    *(u16x4*)(xr + 512 + lane * 4) = o;

    if (lane == 0) {
        float srcx = ((float)x + 0.5f) * (2.f / 128.f) - 1.f;
        float srcy = ((float)y + 0.5f) * (2.f / 128.f) - 1.f;
        xr[768] = f2bf(gx - srcx);
        xr[769] = f2bf(gy - srcy);
        xr[770] = f2bf(conf);
#pragma unroll
        for (int j = 0; j < 9; j++) {
            float invs = 1.f / fmaxf(sqrtf(s2v[j]), 1e-12f);
            xr[771 + j] = f2bf(dotv[j] * inv_na * invs);
        }
#pragma unroll
        for (int k = 780; k < KPAD; k++) xr[k] = 0;
    }
}

// ---------------- conv1x1 as MFMA GEMM: [NPIX x 800] @ [800 x 64] ----------------
__global__ __launch_bounds__(256) void k_gemm1(const unsigned short* __restrict__ xbuf,
                                               const unsigned short* __restrict__ pack,
                                               unsigned short* __restrict__ hpre)
{
    int wave = (blockIdx.x * 256 + threadIdx.x) >> 6;   // pixel tile of 16
    int lane = threadIdx.x & 63;
    if (wave >= NPIX / 16) return;
    int la = lane & 15, lb = lane >> 4;
    f32x4 acc[4] = {{0,0,0,0},{0,0,0,0},{0,0,0,0},{0,0,0,0}};
    const unsigned short* arow = xbuf + (size_t)(wave * 16 + la) * KPAD + lb * 8;
#pragma unroll 5
    for (int ks = 0; ks < K1STEPS; ks++) {
        s16x8 a = *(const s16x8*)(arow + ks * 32);
#pragma unroll
        for (int nt = 0; nt < 4; nt++) {
            s16x8 bv = *(const s16x8*)(pack + ((size_t)(ks * 4 + nt) * 64 + lane) * 8);
            acc[nt] = __builtin_amdgcn_mfma_f32_16x16x32_bf16(a, bv, acc[nt], 0, 0, 0);
        }
    }
    int orow = wave * 16 + lb * 4;
#pragma unroll
    for (int nt = 0; nt < 4; nt++)
#pragma unroll
        for (int r = 0; r < 4; r++)
            hpre[(size_t)(orow + r) * HID + nt * 16 + la] = f2bf(acc[nt][r]);
}

// ---------------- conv3x3 as MFMA implicit-im2col GEMM ----------------
__global__ __launch_bounds__(256) void k_conv3(const unsigned short* __restrict__ hin,
                                               const unsigned short* __restrict__ pack,
                                               unsigned short* __restrict__ hpre)
{
    int wave = (blockIdx.x * 256 + threadIdx.x) >> 6;   // tile: 16 consecutive x
    int lane = threadIdx.x & 63;
    if (wave >= NPIX / 16) return;
    int la = lane & 15, lb = lane >> 4;
    int b = wave >> 10, y = (wave >> 3) & 127, xb = (wave & 7) * 16;
    int xx = xb + la;
    f32x4 acc[4] = {{0,0,0,0},{0,0,0,0},{0,0,0,0},{0,0,0,0}};
#pragma unroll
    for (int ks = 0; ks < K3STEPS; ks++) {
        int tap = ks >> 1;
        int yy = y + tap / 3 - 1;
        int xq = xx + tap % 3 - 1;
        s16x8 a = {0,0,0,0,0,0,0,0};
        if ((unsigned)yy < 128u && (unsigned)xq < 128u)
            a = *(const s16x8*)(hin + ((size_t)((b * 128 + yy) * 128 + xq)) * HID
                                + (ks & 1) * 32 + lb * 8);
#pragma unroll
        for (int nt = 0; nt < 4; nt++) {
            s16x8 bv = *(const s16x8*)(pack + ((size_t)(ks * 4 + nt) * 64 + lane) * 8);
            acc[nt] = __builtin_amdgcn_mfma_f32_16x16x32_bf16(a, bv, acc[nt], 0, 0, 0);
        }
    }
    int orow = wave * 16 + lb * 4;
#pragma unroll
    for (int nt = 0; nt < 4; nt++)
#pragma unroll
        for (int r = 0; r < 4; r++)
            hpre[(size_t)(orow + r) * HID + nt * 16 + la] = f2bf(acc[nt][r]);
}

// ---------------- GroupNorm stats: one block per (b, g) ----------------
__global__ __launch_bounds__(256) void k_gnstats(const unsigned short* __restrict__ hpre,
                                                 float* __restrict__ stats)
{
    int bg = blockIdx.x;            // 16
    int b = bg >> 3, g = bg & 7;
    float s = 0.f, s2 = 0.f;
    const unsigned short* base = hpre + (size_t)b * PIX_PER * HID + g * 8;
    for (int pix = threadIdx.x; pix < PIX_PER; pix += 256) {
        u16x8 v = *(const u16x8*)(base + (size_t)pix * HID);
#pragma unroll
        for (int i = 0; i < 8; i++) {
            float f = bf2f(v[i]);
            s += f; s2 += f * f;
        }
    }
    __shared__ float ls[512];
    ls[threadIdx.x] = s; ls[256 + threadIdx.x] = s2;
    __syncthreads();
    for (int st = 128; st > 0; st >>= 1) {
        if ((int)threadIdx.x < st) {
            ls[threadIdx.x] += ls[threadIdx.x + st];
            ls[256 + threadIdx.x] += ls[256 + threadIdx.x + st];
        }
        __syncthreads();
    }
    if (threadIdx.x == 0) {
        const float inv = 1.f / (float)(PIX_PER * 8);
        float mean = ls[0] * inv;
        float var = fmaxf(ls[256] * inv - mean * mean, 0.f);
        stats[bg * 2] = mean;
        stats[bg * 2 + 1] = rsqrtf(var + 1e-5f);
    }
}

// ---------------- GN apply + exact GELU ----------------
__global__ __launch_bounds__(256) void k_gnapply(const unsigned short* __restrict__ hpre,
                                                 const float* __restrict__ gamma,
                                                 const float* __restrict__ beta,
                                                 const float* __restrict__ stats,
                                                 unsigned short* __restrict__ hn)
{
    int t = blockIdx.x * 256 + threadIdx.x;   // NPIX * 8
    if (t >= NPIX * 8) return;
    int pix = t >> 3, g = t & 7;
    int b = pix >> 14;
    float mean = stats[(b * 8 + g) * 2];
    float rstd = stats[(b * 8 + g) * 2 + 1];
    u16x8 v = *(const u16x8*)(hpre + (size_t)pix * HID + g * 8);
    u16x8 o;
#pragma unroll
    for (int i = 0; i < 8; i++) {
        int c = g * 8 + i;
        float xn = (bf2f(v[i]) - mean) * rstd * gamma[c] + beta[c];
        float ge = 0.5f * xn * (1.f + erff(xn * 0.70710678118654752f));
        o[i] = f2bf(ge);
    }
    *(u16x8*)(hn + (size_t)pix * HID + g * 8) = o;
}

// ---------------- delta/conf heads + epilogue ----------------
__global__ __launch_bounds__(256) void k_final(const unsigned short* __restrict__ hn,
                                               const float* __restrict__ cw,
                                               const float* __restrict__ confp,
                                               const float* __restrict__ dw,
                                               const float* __restrict__ db,
                                               const float* __restrict__ cwgt,
                                               const float* __restrict__ cb,
                                               float* __restrict__ out)
{
    __shared__ float wds[1154];   // 2*576 delta weights + 2 bias
    __shared__ float wcs[577];    // 576 conf weights + 1 bias
    int tid = threadIdx.x;
    for (int i = tid; i < 1152; i += 256) wds[i] = dw[i];
    for (int i = tid; i < 576; i += 256) wcs[i] = cwgt[i];
    if (tid == 0) { wds[1152] = db[0]; wds[1153] = db[1]; wcs[576] = cb[0]; }
    __syncthreads();

    int pix = blockIdx.x * 256 + tid;
    if (pix >= NPIX) return;
    int b = pix >> 14, y = (pix >> 7) & 127, x = pix & 127;

    float d0 = 0.f, d1 = 0.f, c0 = 0.f;
#pragma unroll
    for (int ky = 0; ky < 3; ky++) {
        int yy = y + ky - 1;
        if ((unsigned)yy >= 128u) continue;
#pragma unroll
        for (int kx = 0; kx < 3; kx++) {
            int xq = x + kx - 1;
            if ((unsigned)xq >= 128u) continue;
            const unsigned short* hp = hn + (size_t)((b * 128 + yy) * 128 + xq) * HID;
            int widx = ky * 3 + kx;
#pragma unroll
            for (int c8 = 0; c8 < 8; c8++) {
                u16x8 v = *(const u16x8*)(hp + c8 * 8);
#pragma unroll
                for (int i = 0; i < 8; i++) {
                    float f = bf2f(v[i]);
                    int c = c8 * 8 + i;
                    d0 += f * wds[c * 9 + widx];
                    d1 += f * wds[576 + c * 9 + widx];
                    c0 += f * wcs[c * 9 + widx];
                }
            }
        }
    }
    d0 = tanhf(d0 + wds[1152]);
    d1 = tanhf(d1 + wds[1153]);
    c0 += wcs[576];

    float gx = clean15(cw[(size_t)pix * 2 + 0]);
    float gy = clean15(cw[(size_t)pix * 2 + 1]);
    float fwx = fminf(fmaxf(gx + d0 * 0.0625f, -1.5f), 1.5f);
    float fwy = fminf(fmaxf(gy + d1 * 0.0625f, -1.5f), 1.5f);

    float conf = clean01(confp[pix]);
    float p = fminf(fmaxf(conf, 1e-4f), 1.f - 1e-4f);
    float bl = logf(p) - log1pf(-p);
    float rl = bl + 0.5f * c0;
    float rc = fminf(fmaxf(1.f / (1.f + expf(-rl)), 0.f), 1.f);

    out[(size_t)pix * 2 + 0] = fwx;
    out[(size_t)pix * 2 + 1] = fwy;
    out[(size_t)NPIX * 2 + pix] = rc;
    out[(size_t)NPIX * 2 + NPIX + pix] = rl;
}

// ---------------- launcher ----------------
extern "C" void kernel_launch(void* const* d_in, const int* in_sizes, int n_in,
                              void* d_out, int out_size, void* d_ws, size_t ws_size,
                              hipStream_t stream)
{
    const float* feat_A = (const float*)d_in[0];
    const float* feat_B = (const float*)d_in[1];
    const float* cw     = (const float*)d_in[2];
    const float* conf   = (const float*)d_in[3];
    const float* w1     = (const float*)d_in[4];
    const float* g1     = (const float*)d_in[5];
    const float* b1     = (const float*)d_in[6];
    const float* w2     = (const float*)d_in[7];
    const float* g2     = (const float*)d_in[8];
    const float* b2     = (const float*)d_in[9];
    const float* w3     = (const float*)d_in[10];
    const float* g3     = (const float*)d_in[11];
    const float* b3     = (const float*)d_in[12];
    const float* dw     = (const float*)d_in[13];
    const float* db     = (const float*)d_in[14];
    const float* cwgt   = (const float*)d_in[15];
    const float* cb     = (const float*)d_in[16];
    float* out = (float*)d_out;

    char* w = (char*)d_ws;
    size_t o = 0;
    unsigned short* faT  = (unsigned short*)(w + o); o += (size_t)NPIX * C_ * 2;       // 16 MB
    unsigned short* fbT  = (unsigned short*)(w + o); o += (size_t)NPIX * C_ * 2;       // 16 MB
    unsigned short* xbuf = (unsigned short*)(w + o); o += (size_t)NPIX * KPAD * 2;     // 50 MB
    unsigned short* hpre = (unsigned short*)(w + o); o += (size_t)NPIX * HID * 2;      // 4 MB
    unsigned short* hnA  = (unsigned short*)(w + o); o += (size_t)NPIX * HID * 2;
    unsigned short* hnB  = (unsigned short*)(w + o); o += (size_t)NPIX * HID * 2;
    unsigned short* p1   = (unsigned short*)(w + o); o += (size_t)K1STEPS * 4 * 64 * 8 * 2;
    unsigned short* p2   = (unsigned short*)(w + o); o += (size_t)K3STEPS * 4 * 64 * 8 * 2;
    unsigned short* p3   = (unsigned short*)(w + o); o += (size_t)K3STEPS * 4 * 64 * 8 * 2;
    float* stats = (float*)(w + o);   // 3 * 16 * 2 floats

    k_transpose<<<dim3(PIX_PER / 32, C_ / 32, 4), 256, 0, stream>>>(feat_A, feat_B, faT, fbT);
    k_pack<<<61, 256, 0, stream>>>(w1, w2, w3, p1, p2, p3);
    k_sample<<<NPIX / 4, 256, 0, stream>>>(cw, conf, faT, fbT, xbuf);

    k_gemm1<<<(NPIX / 16) / 4, 256, 0, stream>>>(xbuf, p1, hpre);
    k_gnstats<<<16, 256, 0, stream>>>(hpre, stats);
    k_gnapply<<<(NPIX * 8) / 256, 256, 0, stream>>>(hpre, g1, b1, stats, hnA);

    k_conv3<<<(NPIX / 16) / 4, 256, 0, stream>>>(hnA, p2, hpre);
    k_gnstats<<<16, 256, 0, stream>>>(hpre, stats + 32);
    k_gnapply<<<(NPIX * 8) / 256, 256, 0, stream>>>(hpre, g2, b2, stats + 32, hnB);

    k_conv3<<<(NPIX / 16) / 4, 256, 0, stream>>>(hnB, p3, hpre);
    k_gnstats<<<16, 256, 0, stream>>>(hpre, stats + 64);
    k_gnapply<<<(NPIX * 8) / 256, 256, 0, stream>>>(hpre, g3, b3, stats + 64, hnA);

    k_final<<<NPIX / 256, 256, 0, stream>>>(hnA, cw, conf, dw, db, cwgt, cb, out);
}

// Round 2
// 170.039 us; speedup vs baseline: 1.4917x; 1.4917x over previous
//
#include <hip/hip_runtime.h>
#include <hip/hip_bf16.h>
#include <math.h>

#define B_ 2
#define H_ 128
#define W_ 128
#define C_ 256
#define HID 64
#define PIX_PER (H_*W_)          // 16384
#define NPIX (B_*PIX_PER)        // 32768
#define K1STEPS 25               // 800 / 32 (fa 0-7, wb 8-15, diff 16-23, tail 24)
#define K3STEPS 18               // 576 / 32

using f32x4 = __attribute__((ext_vector_type(4))) float;
using s16x8 = __attribute__((ext_vector_type(8))) short;
using u16x4 = __attribute__((ext_vector_type(4))) unsigned short;
using u16x8 = __attribute__((ext_vector_type(8))) unsigned short;

__device__ __forceinline__ float bf2f(unsigned short u) {
    return __uint_as_float(((unsigned)u) << 16);
}
__device__ __forceinline__ unsigned short f2bf(float f) {
    unsigned u = __float_as_uint(f);
    u += 0x7FFFu + ((u >> 16) & 1u);
    return (unsigned short)(u >> 16);
}
__device__ __forceinline__ float clean15(float v) {
    if (v != v) v = 0.f;
    return fminf(fmaxf(v, -1.5f), 1.5f);
}
__device__ __forceinline__ float clean01(float v) {
    if (v != v) v = 0.f;
    return fminf(fmaxf(v, 0.f), 1.f);
}

// ---------------- transpose NCHW -> NHWC bf16 with nan cleanup ----------------
__global__ __launch_bounds__(256) void k_transpose(const float* __restrict__ A,
                                                   const float* __restrict__ Bm,
                                                   unsigned short* __restrict__ faT,
                                                   unsigned short* __restrict__ fbT)
{
    __shared__ float tile[32][33];
    int hw0 = blockIdx.x * 32;
    int c0  = blockIdx.y * 32;
    int z   = blockIdx.z;            // b*2 + which
    int b   = z >> 1;
    const float* src = (z & 1) ? Bm : A;
    unsigned short* dst = (z & 1) ? fbT : faT;
    int tx = threadIdx.x & 31, ty = threadIdx.x >> 5;   // 32 x 8
    const float* s = src + ((size_t)b * C_ + c0) * (size_t)PIX_PER + hw0;
#pragma unroll
    for (int i = 0; i < 32; i += 8) {
        float v = s[(size_t)(ty + i) * PIX_PER + tx];
        if (!isfinite(v)) v = 0.f;
        tile[ty + i][tx] = v;
    }
    __syncthreads();
    unsigned short* d = dst + ((size_t)b * PIX_PER + hw0) * C_ + c0;
#pragma unroll
    for (int i = 0; i < 32; i += 8)
        d[(size_t)(ty + i) * C_ + tx] = f2bf(tile[tx][ty + i]);
}

// ---------------- weight packing into MFMA B-fragment order ----------------
__global__ __launch_bounds__(256) void k_pack(const float* __restrict__ w1,
                                              const float* __restrict__ w2,
                                              const float* __restrict__ w3,
                                              unsigned short* __restrict__ p1,
                                              unsigned short* __restrict__ p2,
                                              unsigned short* __restrict__ p3)
{
    int t = blockIdx.x * 256 + threadIdx.x;
    if (t < 6400) {                                   // enc1: 25 ksteps
        int lane = t & 63, nt = (t >> 6) & 3, ks = t >> 8;
        int n = nt * 16 + (lane & 15);
        int kb = ks * 32 + 8 * (lane >> 4);
#pragma unroll
        for (int j = 0; j < 8; j++) {
            int k = kb + j;
            p1[(size_t)t * 8 + j] = (k < 780) ? f2bf(w1[(size_t)n * 780 + k]) : (unsigned short)0;
        }
    } else if (t < 6400 + 2 * 4608) {                 // enc2/enc3: 18 ksteps each
        int which = (t - 6400) / 4608;
        int idx = (t - 6400) % 4608;
        const float* w = which ? w3 : w2;
        unsigned short* p = which ? p3 : p2;
        int lane = idx & 63, nt = (idx >> 6) & 3, ks = idx >> 8;
        int n = nt * 16 + (lane & 15);
        int tap = ks >> 1;
        int ky = tap / 3, kx = tap % 3;
#pragma unroll
        for (int j = 0; j < 8; j++) {
            int c = (ks & 1) * 32 + 8 * (lane >> 4) + j;
            p[(size_t)idx * 8 + j] = f2bf(w[(((size_t)n * 64 + c) * 3 + ky) * 3 + kx]);
        }
    }
}

// ---------------- sampling + correlation (4 pixels/wave, 16 lanes/pixel) ----------------
// Key identity: the 9 offsets are exact +-1 pixel shifts, so all 36 bilinear
// taps live in one 4x4 neighborhood sharing a single (wx,wy); border clamps
// collapse both taps of an offset to the same texel, so no weight fixup needed.
__global__ __launch_bounds__(256) void k_sample(const float* __restrict__ cw,
                                                const float* __restrict__ confp,
                                                const unsigned short* __restrict__ faT,
                                                const unsigned short* __restrict__ fbT,
                                                unsigned short* __restrict__ wbbuf,
                                                unsigned short* __restrict__ tail)
{
    int wave = (blockIdx.x * 256 + threadIdx.x) >> 6;
    int lane = threadIdx.x & 63;
    int pg = lane >> 4, sub = lane & 15;
    int wid = wave * 4 + pg;
    int b = wid >> 14, y = (wid >> 7) & 127, x = wid & 127;

    float gx = clean15(cw[(size_t)wid * 2 + 0]);
    float gy = clean15(cw[(size_t)wid * 2 + 1]);
    float conf = clean01(confp[wid]);

    float pxu = (gx + 1.f) * 64.f - 0.5f;
    float pyu = (gy + 1.f) * 64.f - 0.5f;
    float x0f = floorf(pxu), y0f = floorf(pyu);
    float wx = pxu - x0f, wy = pyu - y0f;
    int x0 = (int)x0f, y0 = (int)y0f;
    int cx[4], cy[4];
#pragma unroll
    for (int k = 0; k < 4; k++) {
        cx[k] = min(max(x0 - 1 + k, 0), 127);
        cy[k] = min(max(y0 - 1 + k, 0), 127);
    }
    float w00 = (1.f - wx) * (1.f - wy), w01 = wx * (1.f - wy);
    float w10 = (1.f - wx) * wy,         w11 = wx * wy;

    int toff[4][4];
#pragma unroll
    for (int m = 0; m < 4; m++)
#pragma unroll
        for (int k = 0; k < 4; k++)
            toff[m][k] = (cy[m] * 128 + cx[k]) * C_;

    const unsigned short* fbB = fbT + (size_t)b * PIX_PER * C_ + sub * 4;
    const unsigned short* faB = faT + (size_t)wid * C_ + sub * 4;

    float dot[9] = {0,0,0,0,0,0,0,0,0}, s2[9] = {0,0,0,0,0,0,0,0,0};
    float fa2 = 0.f;

#pragma unroll
    for (int cn = 0; cn < 4; cn++) {
        int co = cn * 64;
        float t[4][4][4];
#pragma unroll
        for (int m = 0; m < 4; m++)
#pragma unroll
            for (int k = 0; k < 4; k++) {
                u16x4 v = *(const u16x4*)(fbB + toff[m][k] + co);
#pragma unroll
                for (int i = 0; i < 4; i++) t[m][k][i] = bf2f(v[i]);
            }
        float fa[4];
        {
            u16x4 v = *(const u16x4*)(faB + co);
#pragma unroll
            for (int i = 0; i < 4; i++) { fa[i] = bf2f(v[i]); fa2 += fa[i] * fa[i]; }
        }
        u16x4 wbo;
#pragma unroll
        for (int j = 0; j < 9; j++) {
            int dy = j / 3, dx = j % 3;
#pragma unroll
            for (int i = 0; i < 4; i++) {
                float s = w00 * t[dy][dx][i] + w01 * t[dy][dx+1][i]
                        + w10 * t[dy+1][dx][i] + w11 * t[dy+1][dx+1][i];
                dot[j] += fa[i] * s;
                s2[j]  += s * s;
                if (j == 4) wbo[i] = f2bf(s);
            }
        }
        *(u16x4*)(wbbuf + (size_t)wid * C_ + co + sub * 4) = wbo;
    }

    // reduce across the 16 lanes of this pixel group
#pragma unroll
    for (int m = 1; m < 16; m <<= 1) {
        fa2 += __shfl_xor(fa2, m);
#pragma unroll
        for (int j = 0; j < 9; j++) {
            dot[j] += __shfl_xor(dot[j], m);
            s2[j]  += __shfl_xor(s2[j], m);
        }
    }

    if (sub == 0) {
        float inv_na = rsqrtf(fmaxf(fa2, 1e-24f));
        float srcx = ((float)x + 0.5f) * 0.015625f - 1.f;
        float srcy = ((float)y + 0.5f) * 0.015625f - 1.f;
        u16x8 t0, t1, tz;
        t0[0] = f2bf(gx - srcx);
        t0[1] = f2bf(gy - srcy);
        t0[2] = f2bf(conf);
        float corr[9];
#pragma unroll
        for (int j = 0; j < 9; j++)
            corr[j] = dot[j] * inv_na * rsqrtf(fmaxf(s2[j], 1e-24f));
#pragma unroll
        for (int j = 0; j < 5; j++) t0[3 + j] = f2bf(corr[j]);
#pragma unroll
        for (int j = 0; j < 4; j++) t1[j] = f2bf(corr[5 + j]);
#pragma unroll
        for (int j = 4; j < 8; j++) t1[j] = 0;
#pragma unroll
        for (int j = 0; j < 8; j++) tz[j] = 0;
        unsigned short* tr = tail + (size_t)wid * 32;
        *(u16x8*)(tr)      = t0;
        *(u16x8*)(tr + 8)  = t1;
        *(u16x8*)(tr + 16) = tz;
        *(u16x8*)(tr + 24) = tz;
    }
}

// ---------------- conv1x1 as MFMA GEMM, A assembled on the fly ----------------
__global__ __launch_bounds__(256) void k_gemm1(const unsigned short* __restrict__ faT,
                                               const unsigned short* __restrict__ wbbuf,
                                               const unsigned short* __restrict__ tail,
                                               const unsigned short* __restrict__ pack,
                                               unsigned short* __restrict__ hpre)
{
    int wave = (blockIdx.x * 256 + threadIdx.x) >> 6;
    int lane = threadIdx.x & 63;
    int la = lane & 15, lb = lane >> 4;
    int row = wave * 16 + la;
    const unsigned short* fa_row = faT   + (size_t)row * C_ + lb * 8;
    const unsigned short* wb_row = wbbuf + (size_t)row * C_ + lb * 8;
    f32x4 acc[4] = {{0,0,0,0},{0,0,0,0},{0,0,0,0},{0,0,0,0}};

#pragma unroll
    for (int ks = 0; ks < 8; ks++) {
        s16x8 a = *(const s16x8*)(fa_row + ks * 32);
#pragma unroll
        for (int nt = 0; nt < 4; nt++)
            acc[nt] = __builtin_amdgcn_mfma_f32_16x16x32_bf16(a,
                *(const s16x8*)(pack + ((size_t)(ks * 4 + nt) * 64 + lane) * 8), acc[nt], 0, 0, 0);
    }
#pragma unroll
    for (int ks = 0; ks < 8; ks++) {
        s16x8 a = *(const s16x8*)(wb_row + ks * 32);
#pragma unroll
        for (int nt = 0; nt < 4; nt++)
            acc[nt] = __builtin_amdgcn_mfma_f32_16x16x32_bf16(a,
                *(const s16x8*)(pack + ((size_t)((ks + 8) * 4 + nt) * 64 + lane) * 8), acc[nt], 0, 0, 0);
    }
#pragma unroll
    for (int ks = 0; ks < 8; ks++) {
        u16x8 av = *(const u16x8*)(fa_row + ks * 32);
        u16x8 bv = *(const u16x8*)(wb_row + ks * 32);
        s16x8 a;
#pragma unroll
        for (int j = 0; j < 8; j++)
            a[j] = (short)f2bf(fabsf(bf2f(av[j]) - bf2f(bv[j])));
#pragma unroll
        for (int nt = 0; nt < 4; nt++)
            acc[nt] = __builtin_amdgcn_mfma_f32_16x16x32_bf16(a,
                *(const s16x8*)(pack + ((size_t)((ks + 16) * 4 + nt) * 64 + lane) * 8), acc[nt], 0, 0, 0);
    }
    {
        s16x8 a = *(const s16x8*)(tail + (size_t)row * 32 + lb * 8);
#pragma unroll
        for (int nt = 0; nt < 4; nt++)
            acc[nt] = __builtin_amdgcn_mfma_f32_16x16x32_bf16(a,
                *(const s16x8*)(pack + ((size_t)(24 * 4 + nt) * 64 + lane) * 8), acc[nt], 0, 0, 0);
    }

    int orow = wave * 16 + lb * 4;
#pragma unroll
    for (int nt = 0; nt < 4; nt++)
#pragma unroll
        for (int r = 0; r < 4; r++)
            hpre[(size_t)(orow + r) * HID + nt * 16 + la] = f2bf(acc[nt][r]);
}

// ---------------- conv3x3 as MFMA implicit-im2col GEMM ----------------
__global__ __launch_bounds__(256) void k_conv3(const unsigned short* __restrict__ hin,
                                               const unsigned short* __restrict__ pack,
                                               unsigned short* __restrict__ hpre)
{
    int wave = (blockIdx.x * 256 + threadIdx.x) >> 6;
    int lane = threadIdx.x & 63;
    int la = lane & 15, lb = lane >> 4;
    int b = wave >> 10, y = (wave >> 3) & 127, xb = (wave & 7) * 16;
    int xx = xb + la;
    f32x4 acc[4] = {{0,0,0,0},{0,0,0,0},{0,0,0,0},{0,0,0,0}};
#pragma unroll
    for (int ks = 0; ks < K3STEPS; ks++) {
        int tap = ks >> 1;
        int yy = y + tap / 3 - 1;
        int xq = xx + tap % 3 - 1;
        s16x8 a = {0,0,0,0,0,0,0,0};
        if ((unsigned)yy < 128u && (unsigned)xq < 128u)
            a = *(const s16x8*)(hin + ((size_t)((b * 128 + yy) * 128 + xq)) * HID
                                + (ks & 1) * 32 + lb * 8);
#pragma unroll
        for (int nt = 0; nt < 4; nt++)
            acc[nt] = __builtin_amdgcn_mfma_f32_16x16x32_bf16(a,
                *(const s16x8*)(pack + ((size_t)(ks * 4 + nt) * 64 + lane) * 8), acc[nt], 0, 0, 0);
    }
    int orow = wave * 16 + lb * 4;
#pragma unroll
    for (int nt = 0; nt < 4; nt++)
#pragma unroll
        for (int r = 0; r < 4; r++)
            hpre[(size_t)(orow + r) * HID + nt * 16 + la] = f2bf(acc[nt][r]);
}

// ---------------- GN partial stats: 512 blocks ----------------
__global__ __launch_bounds__(256) void k_gnpart(const unsigned short* __restrict__ hpre,
                                                float* __restrict__ pbuf)
{
    int sl = blockIdx.x;             // 32 slices
    int bg = blockIdx.y;             // 16 (b,g)
    int b = bg >> 3, g = bg & 7;
    const unsigned short* base = hpre + ((size_t)b * PIX_PER + sl * 512) * HID + g * 8;
    float s = 0.f, s2 = 0.f;
#pragma unroll
    for (int it = 0; it < 2; it++) {
        int pix = it * 256 + threadIdx.x;
        u16x8 v = *(const u16x8*)(base + (size_t)pix * HID);
#pragma unroll
        for (int i = 0; i < 8; i++) {
            float f = bf2f(v[i]);
            s += f; s2 += f * f;
        }
    }
    __shared__ float ls[512];
    ls[threadIdx.x] = s; ls[256 + threadIdx.x] = s2;
    __syncthreads();
    for (int st = 128; st > 0; st >>= 1) {
        if ((int)threadIdx.x < st) {
            ls[threadIdx.x] += ls[threadIdx.x + st];
            ls[256 + threadIdx.x] += ls[256 + threadIdx.x + st];
        }
        __syncthreads();
    }
    if (threadIdx.x == 0) {
        pbuf[bg * 64 + sl * 2]     = ls[0];
        pbuf[bg * 64 + sl * 2 + 1] = ls[256];
    }
}

// ---------------- GN finalize (fold) + apply + exact GELU ----------------
__global__ __launch_bounds__(256) void k_gnapply(const unsigned short* __restrict__ hpre,
                                                 const float* __restrict__ gamma,
                                                 const float* __restrict__ beta,
                                                 const float* __restrict__ pbuf,
                                                 unsigned short* __restrict__ hn)
{
    int pix0 = blockIdx.x * 32;
    int b = pix0 >> 14;
    __shared__ float sm[16];
    if (threadIdx.x < 8) {
        int g = threadIdx.x;
        float s = 0.f, s2 = 0.f;
#pragma unroll
        for (int sl = 0; sl < 32; sl++) {
            s  += pbuf[(b * 8 + g) * 64 + sl * 2];
            s2 += pbuf[(b * 8 + g) * 64 + sl * 2 + 1];
        }
        const float inv = 1.f / 131072.f;
        float mean = s * inv;
        float var = fmaxf(s2 * inv - mean * mean, 0.f);
        sm[g * 2] = mean;
        sm[g * 2 + 1] = rsqrtf(var + 1e-5f);
    }
    __syncthreads();
    int t = blockIdx.x * 256 + threadIdx.x;
    int pix = t >> 3, g = t & 7;
    float mean = sm[g * 2], rstd = sm[g * 2 + 1];
    u16x8 v = *(const u16x8*)(hpre + (size_t)pix * HID + g * 8);
    u16x8 o;
#pragma unroll
    for (int i = 0; i < 8; i++) {
        int c = g * 8 + i;
        float xn = (bf2f(v[i]) - mean) * rstd * gamma[c] + beta[c];
        float ge = 0.5f * xn * (1.f + erff(xn * 0.70710678118654752f));
        o[i] = f2bf(ge);
    }
    *(u16x8*)(hn + (size_t)pix * HID + g * 8) = o;
}

// ---------------- delta/conf heads + epilogue (8 threads / pixel) ----------------
__global__ __launch_bounds__(256) void k_final(const unsigned short* __restrict__ hn,
                                               const float* __restrict__ cw,
                                               const float* __restrict__ confp,
                                               const float* __restrict__ dw,
                                               const float* __restrict__ db,
                                               const float* __restrict__ cwgt,
                                               const float* __restrict__ cb,
                                               float* __restrict__ out)
{
    __shared__ float wds[1154];
    __shared__ float wcs[577];
    int tid = threadIdx.x;
    for (int i = tid; i < 1152; i += 256) wds[i] = dw[i];
    for (int i = tid; i < 576; i += 256) wcs[i] = cwgt[i];
    if (tid == 0) { wds[1152] = db[0]; wds[1153] = db[1]; wcs[576] = cb[0]; }
    __syncthreads();

    int t = blockIdx.x * 256 + tid;
    int pix = t >> 3, part = t & 7;
    int b = pix >> 14, y = (pix >> 7) & 127, x = pix & 127;

    float d0 = 0.f, d1 = 0.f, c0 = 0.f;
#pragma unroll
    for (int ky = 0; ky < 3; ky++) {
        int yy = y + ky - 1;
        if ((unsigned)yy >= 128u) continue;
#pragma unroll
        for (int kx = 0; kx < 3; kx++) {
            int xq = x + kx - 1;
            if ((unsigned)xq >= 128u) continue;
            const unsigned short* hp = hn + (size_t)((b * 128 + yy) * 128 + xq) * HID + part * 8;
            int widx = ky * 3 + kx;
            u16x8 v = *(const u16x8*)hp;
#pragma unroll
            for (int i = 0; i < 8; i++) {
                float f = bf2f(v[i]);
                int c = part * 8 + i;
                d0 += f * wds[c * 9 + widx];
                d1 += f * wds[576 + c * 9 + widx];
                c0 += f * wcs[c * 9 + widx];
            }
        }
    }
#pragma unroll
    for (int m = 1; m < 8; m <<= 1) {
        d0 += __shfl_xor(d0, m);
        d1 += __shfl_xor(d1, m);
        c0 += __shfl_xor(c0, m);
    }
    if (part == 0) {
        d0 = tanhf(d0 + wds[1152]);
        d1 = tanhf(d1 + wds[1153]);
        c0 += wcs[576];

        float gx = clean15(cw[(size_t)pix * 2 + 0]);
        float gy = clean15(cw[(size_t)pix * 2 + 1]);
        float fwx = fminf(fmaxf(gx + d0 * 0.0625f, -1.5f), 1.5f);
        float fwy = fminf(fmaxf(gy + d1 * 0.0625f, -1.5f), 1.5f);

        float conf = clean01(confp[pix]);
        float p = fminf(fmaxf(conf, 1e-4f), 1.f - 1e-4f);
        float bl = logf(p) - log1pf(-p);
        float rl = bl + 0.5f * c0;
        float rc = fminf(fmaxf(1.f / (1.f + expf(-rl)), 0.f), 1.f);

        out[(size_t)pix * 2 + 0] = fwx;
        out[(size_t)pix * 2 + 1] = fwy;
        out[(size_t)NPIX * 2 + pix] = rc;
        out[(size_t)NPIX * 2 + NPIX + pix] = rl;
    }
}

// ---------------- launcher ----------------
extern "C" void kernel_launch(void* const* d_in, const int* in_sizes, int n_in,
                              void* d_out, int out_size, void* d_ws, size_t ws_size,
                              hipStream_t stream)
{
    const float* feat_A = (const float*)d_in[0];
    const float* feat_B = (const float*)d_in[1];
    const float* cw     = (const float*)d_in[2];
    const float* conf   = (const float*)d_in[3];
    const float* w1     = (const float*)d_in[4];
    const float* g1     = (const float*)d_in[5];
    const float* b1     = (const float*)d_in[6];
    const float* w2     = (const float*)d_in[7];
    const float* g2     = (const float*)d_in[8];
    const float* b2     = (const float*)d_in[9];
    const float* w3     = (const float*)d_in[10];
    const float* g3     = (const float*)d_in[11];
    const float* b3     = (const float*)d_in[12];
    const float* dw     = (const float*)d_in[13];
    const float* db     = (const float*)d_in[14];
    const float* cwgt   = (const float*)d_in[15];
    const float* cb     = (const float*)d_in[16];
    float* out = (float*)d_out;

    char* w = (char*)d_ws;
    size_t o = 0;
    unsigned short* faT  = (unsigned short*)(w + o); o += (size_t)NPIX * C_ * 2;     // 16 MB
    unsigned short* fbT  = (unsigned short*)(w + o); o += (size_t)NPIX * C_ * 2;     // 16 MB
    unsigned short* wbb  = (unsigned short*)(w + o); o += (size_t)NPIX * C_ * 2;     // 16 MB
    unsigned short* tail = (unsigned short*)(w + o); o += (size_t)NPIX * 32 * 2;     // 2 MB
    unsigned short* hpre = (unsigned short*)(w + o); o += (size_t)NPIX * HID * 2;    // 4 MB
    unsigned short* hnA  = (unsigned short*)(w + o); o += (size_t)NPIX * HID * 2;
    unsigned short* hnB  = (unsigned short*)(w + o); o += (size_t)NPIX * HID * 2;
    unsigned short* p1   = (unsigned short*)(w + o); o += (size_t)K1STEPS * 4 * 64 * 8 * 2;
    unsigned short* p2   = (unsigned short*)(w + o); o += (size_t)K3STEPS * 4 * 64 * 8 * 2;
    unsigned short* p3   = (unsigned short*)(w + o); o += (size_t)K3STEPS * 4 * 64 * 8 * 2;
    float* pbuf = (float*)(w + o);    // 16*32*2 floats

    k_transpose<<<dim3(PIX_PER / 32, C_ / 32, 4), 256, 0, stream>>>(feat_A, feat_B, faT, fbT);
    k_pack<<<61, 256, 0, stream>>>(w1, w2, w3, p1, p2, p3);
    k_sample<<<NPIX / 16, 256, 0, stream>>>(cw, conf, faT, fbT, wbb, tail);

    k_gemm1<<<(NPIX / 16) / 4, 256, 0, stream>>>(faT, wbb, tail, p1, hpre);
    k_gnpart<<<dim3(32, 16), 256, 0, stream>>>(hpre, pbuf);
    k_gnapply<<<NPIX / 32, 256, 0, stream>>>(hpre, g1, b1, pbuf, hnA);

    k_conv3<<<(NPIX / 16) / 4, 256, 0, stream>>>(hnA, p2, hpre);
    k_gnpart<<<dim3(32, 16), 256, 0, stream>>>(hpre, pbuf);
    k_gnapply<<<NPIX / 32, 256, 0, stream>>>(hpre, g2, b2, pbuf, hnB);

    k_conv3<<<(NPIX / 16) / 4, 256, 0, stream>>>(hnB, p3, hpre);
    k_gnpart<<<dim3(32, 16), 256, 0, stream>>>(hpre, pbuf);
    k_gnapply<<<NPIX / 32, 256, 0, stream>>>(hpre, g3, b3, pbuf, hnA);

    k_final<<<NPIX * 8 / 256, 256, 0, stream>>>(hnA, cw, conf, dw, db, cwgt, cb, out);
}

// Round 3
// 151.654 us; speedup vs baseline: 1.6726x; 1.1212x over previous
//
#include <hip/hip_runtime.h>
#include <hip/hip_bf16.h>
#include <math.h>

#define B_ 2
#define H_ 128
#define W_ 128
#define C_ 256
#define HID 64
#define PIX_PER (H_*W_)          // 16384
#define NPIX (B_*PIX_PER)        // 32768
#define K1STEPS 25               // 800 / 32 (fa 0-7, wb 8-15, diff 16-23, tail 24)
#define K3STEPS 18               // 576 / 32

using f32x4 = __attribute__((ext_vector_type(4))) float;
using s16x8 = __attribute__((ext_vector_type(8))) short;
using u16x2 = __attribute__((ext_vector_type(2))) unsigned short;
using u16x4 = __attribute__((ext_vector_type(4))) unsigned short;
using u16x8 = __attribute__((ext_vector_type(8))) unsigned short;

__device__ __forceinline__ float bf2f(unsigned short u) {
    return __uint_as_float(((unsigned)u) << 16);
}
__device__ __forceinline__ unsigned short f2bf(float f) {
    unsigned u = __float_as_uint(f);
    u += 0x7FFFu + ((u >> 16) & 1u);
    return (unsigned short)(u >> 16);
}
__device__ __forceinline__ float clean15(float v) {
    if (v != v) v = 0.f;
    return fminf(fmaxf(v, -1.5f), 1.5f);
}
__device__ __forceinline__ float clean01(float v) {
    if (v != v) v = 0.f;
    return fminf(fmaxf(v, 0.f), 1.f);
}

// ---------------- transpose NCHW -> NHWC bf16 with nan cleanup ----------------
__global__ __launch_bounds__(256) void k_transpose(const float* __restrict__ A,
                                                   const float* __restrict__ Bm,
                                                   unsigned short* __restrict__ faT,
                                                   unsigned short* __restrict__ fbT)
{
    __shared__ float tile[32][33];
    int hw0 = blockIdx.x * 32;
    int c0  = blockIdx.y * 32;
    int z   = blockIdx.z;            // b*2 + which
    int b   = z >> 1;
    const float* src = (z & 1) ? Bm : A;
    unsigned short* dst = (z & 1) ? fbT : faT;
    int tx = threadIdx.x & 31, ty = threadIdx.x >> 5;   // 32 x 8
    const float* s = src + ((size_t)b * C_ + c0) * (size_t)PIX_PER + hw0;
#pragma unroll
    for (int i = 0; i < 32; i += 8) {
        float v = s[(size_t)(ty + i) * PIX_PER + tx];
        if (!isfinite(v)) v = 0.f;
        tile[ty + i][tx] = v;
    }
    __syncthreads();
    // write u16x2: thread covers channels c0+2tx, c0+2tx+1 at rows ty+i
    unsigned short* d = dst + ((size_t)b * PIX_PER + hw0) * C_ + c0;
#pragma unroll
    for (int i = 0; i < 32; i += 8) {
        int hwl = ty + i;
        u16x2 o;
        o[0] = f2bf(tile[2 * tx][hwl]);
        o[1] = f2bf(tile[2 * tx + 1][hwl]);
        *(u16x2*)(d + (size_t)hwl * C_ + 2 * tx) = o;
    }
}

// ---------------- weight packing into MFMA B-fragment order ----------------
__global__ __launch_bounds__(256) void k_pack(const float* __restrict__ w1,
                                              const float* __restrict__ w2,
                                              const float* __restrict__ w3,
                                              unsigned short* __restrict__ p1,
                                              unsigned short* __restrict__ p2,
                                              unsigned short* __restrict__ p3)
{
    int t = blockIdx.x * 256 + threadIdx.x;
    if (t < 6400) {                                   // enc1: 25 ksteps
        int lane = t & 63, nt = (t >> 6) & 3, ks = t >> 8;
        int n = nt * 16 + (lane & 15);
        int kb = ks * 32 + 8 * (lane >> 4);
#pragma unroll
        for (int j = 0; j < 8; j++) {
            int k = kb + j;
            p1[(size_t)t * 8 + j] = (k < 780) ? f2bf(w1[(size_t)n * 780 + k]) : (unsigned short)0;
        }
    } else if (t < 6400 + 2 * 4608) {                 // enc2/enc3: 18 ksteps each
        int which = (t - 6400) / 4608;
        int idx = (t - 6400) % 4608;
        const float* w = which ? w3 : w2;
        unsigned short* p = which ? p3 : p2;
        int lane = idx & 63, nt = (idx >> 6) & 3, ks = idx >> 8;
        int n = nt * 16 + (lane & 15);
        int tap = ks >> 1;
        int ky = tap / 3, kx = tap % 3;
#pragma unroll
        for (int j = 0; j < 8; j++) {
            int c = (ks & 1) * 32 + 8 * (lane >> 4) + j;
            p[(size_t)idx * 8 + j] = f2bf(w[(((size_t)n * 64 + c) * 3 + ky) * 3 + kx]);
        }
    }
}

// ---------------- sampling + correlation: 1 wave/pixel, 4 ch/lane ----------------
// Identity: the 9 offsets are exact +-1 pixel shifts -> all 36 bilinear taps
// live in one 4x4 neighborhood sharing one (wx,wy); border clamps collapse
// taps so no weight fixup is needed (validated rounds 1-2).
// Row decomposition: rx[r][dx] = lerp_x; A=fa.rx, P=rx^2, Q=rx_r.rx_{r+1}
// accumulated per lane; dot/s2 formed per-lane (weights wave-uniform) so the
// shuffle reduction stays at 19 values.
__global__ __launch_bounds__(256, 4) void k_sample(const float* __restrict__ cw,
                                                   const float* __restrict__ confp,
                                                   const unsigned short* __restrict__ faT,
                                                   const unsigned short* __restrict__ fbT,
                                                   unsigned short* __restrict__ wbbuf,
                                                   unsigned short* __restrict__ tail)
{
    int wid = (blockIdx.x * 256 + threadIdx.x) >> 6;
    int lane = threadIdx.x & 63;
    int b = wid >> 14, y = (wid >> 7) & 127, x = wid & 127;

    float gx = clean15(cw[(size_t)wid * 2 + 0]);
    float gy = clean15(cw[(size_t)wid * 2 + 1]);

    float pxu = (gx + 1.f) * 64.f - 0.5f;
    float pyu = (gy + 1.f) * 64.f - 0.5f;
    float x0f = floorf(pxu), y0f = floorf(pyu);
    float wx = pxu - x0f, wy = pyu - y0f;
    int x0 = (int)x0f, y0 = (int)y0f;
    int cx[4], cy[4];
#pragma unroll
    for (int k = 0; k < 4; k++) {
        cx[k] = min(max(x0 - 1 + k, 0), 127);
        cy[k] = min(max(y0 - 1 + k, 0), 127);
    }

    const unsigned short* fbB = fbT + (size_t)b * PIX_PER * C_ + lane * 4;
    u16x4 tp[4][4];
#pragma unroll
    for (int m = 0; m < 4; m++)
#pragma unroll
        for (int k = 0; k < 4; k++)
            tp[m][k] = *(const u16x4*)(fbB + (size_t)(cy[m] * 128 + cx[k]) * C_);

    float fa[4], fa2 = 0.f;
    {
        u16x4 v = *(const u16x4*)(faT + (size_t)wid * C_ + lane * 4);
#pragma unroll
        for (int i = 0; i < 4; i++) { fa[i] = bf2f(v[i]); fa2 += fa[i] * fa[i]; }
    }

    float A[4][3], P[4][3], Q[3][3], rxp[3][4], wbv[4];
#pragma unroll
    for (int r = 0; r < 4; r++) {
        float rx[3][4];
#pragma unroll
        for (int dx = 0; dx < 3; dx++)
#pragma unroll
            for (int i = 0; i < 4; i++) {
                float t0 = bf2f(tp[r][dx][i]);
                float t1 = bf2f(tp[r][dx + 1][i]);
                rx[dx][i] = t0 + wx * (t1 - t0);
            }
#pragma unroll
        for (int dx = 0; dx < 3; dx++) {
            float a = 0.f, p = 0.f;
#pragma unroll
            for (int i = 0; i < 4; i++) { a += fa[i] * rx[dx][i]; p += rx[dx][i] * rx[dx][i]; }
            A[r][dx] = a; P[r][dx] = p;
            if (r > 0) {
                float q = 0.f;
#pragma unroll
                for (int i = 0; i < 4; i++) q += rxp[dx][i] * rx[dx][i];
                Q[r - 1][dx] = q;
            }
        }
        if (r == 1) {
#pragma unroll
            for (int i = 0; i < 4; i++) wbv[i] = rx[1][i];
        }
        if (r == 2) {
#pragma unroll
            for (int i = 0; i < 4; i++) wbv[i] += wy * (rx[1][i] - wbv[i]);
        }
        if (r < 3) {
#pragma unroll
            for (int dx = 0; dx < 3; dx++)
#pragma unroll
                for (int i = 0; i < 4; i++) rxp[dx][i] = rx[dx][i];
        }
    }

    u16x4 wbo;
#pragma unroll
    for (int i = 0; i < 4; i++) wbo[i] = f2bf(wbv[i]);
    *(u16x4*)(wbbuf + (size_t)wid * C_ + lane * 4) = wbo;

    float red[19];
    float u0 = (1.f - wy) * (1.f - wy), u1 = 2.f * wy * (1.f - wy), u2 = wy * wy;
#pragma unroll
    for (int j = 0; j < 9; j++) {
        int dy = j / 3, dx = j % 3;
        red[j]     = A[dy][dx] + wy * (A[dy + 1][dx] - A[dy][dx]);
        red[9 + j] = u0 * P[dy][dx] + u1 * Q[dy][dx] + u2 * P[dy + 1][dx];
    }
    red[18] = fa2;
#pragma unroll
    for (int m = 1; m < 64; m <<= 1)
#pragma unroll
        for (int j = 0; j < 19; j++)
            red[j] += __shfl_xor(red[j], m);

    if (lane == 0) {
        float conf = clean01(confp[wid]);
        float inv_na = rsqrtf(fmaxf(red[18], 1e-24f));
        float srcx = ((float)x + 0.5f) * 0.015625f - 1.f;
        float srcy = ((float)y + 0.5f) * 0.015625f - 1.f;
        u16x8 t0, t1, tz;
        t0[0] = f2bf(gx - srcx);
        t0[1] = f2bf(gy - srcy);
        t0[2] = f2bf(conf);
#pragma unroll
        for (int j = 0; j < 5; j++)
            t0[3 + j] = f2bf(red[j] * inv_na * rsqrtf(fmaxf(red[9 + j], 1e-24f)));
#pragma unroll
        for (int j = 0; j < 4; j++)
            t1[j] = f2bf(red[5 + j] * inv_na * rsqrtf(fmaxf(red[14 + j], 1e-24f)));
#pragma unroll
        for (int j = 4; j < 8; j++) t1[j] = 0;
#pragma unroll
        for (int j = 0; j < 8; j++) tz[j] = 0;
        unsigned short* tr = tail + (size_t)wid * 32;
        *(u16x8*)(tr)      = t0;
        *(u16x8*)(tr + 8)  = t1;
        *(u16x8*)(tr + 16) = tz;
        *(u16x8*)(tr + 24) = tz;
    }
}

// ---- GN partial-stats epilogue shared by gemm1/conv3 (per-block partials) ----
// acc[nt][r]: channel c = nt*16+la, group g = 2*nt + (la>>3). Block covers 64
// consecutive pixels (same b). pbuf[bid][g] = {sum, sumsq} over block pixels.
__device__ __forceinline__ void gn_epilogue(const f32x4 acc[4], float* lds,
                                            float* __restrict__ pbuf, int bid,
                                            int la, int lb, int wv)
{
    int d = la >> 3;
    int slot = wv * 32 + lb * 8 + (la & 7);
#pragma unroll
    for (int nt = 0; nt < 4; nt++) {
        float s  = acc[nt][0] + acc[nt][1] + acc[nt][2] + acc[nt][3];
        float s2 = acc[nt][0] * acc[nt][0] + acc[nt][1] * acc[nt][1]
                 + acc[nt][2] * acc[nt][2] + acc[nt][3] * acc[nt][3];
        int g = nt * 2 + d;
        lds[(g * 128 + slot) * 2 + 0] = s;
        lds[(g * 128 + slot) * 2 + 1] = s2;
    }
    __syncthreads();
    int tid = threadIdx.x;
    int g = tid >> 5, i = tid & 31;
    float s  = lds[(g * 128 + i) * 2]     + lds[(g * 128 + i + 32) * 2]
             + lds[(g * 128 + i + 64) * 2] + lds[(g * 128 + i + 96) * 2];
    float s2 = lds[(g * 128 + i) * 2 + 1]     + lds[(g * 128 + i + 32) * 2 + 1]
             + lds[(g * 128 + i + 64) * 2 + 1] + lds[(g * 128 + i + 96) * 2 + 1];
#pragma unroll
    for (int m = 1; m < 32; m <<= 1) { s += __shfl_xor(s, m); s2 += __shfl_xor(s2, m); }
    if (i == 0) {
        pbuf[(bid * 8 + g) * 2]     = s;
        pbuf[(bid * 8 + g) * 2 + 1] = s2;
    }
}

// ---------------- conv1x1 as MFMA GEMM, A assembled on the fly ----------------
__global__ __launch_bounds__(256) void k_gemm1(const unsigned short* __restrict__ faT,
                                               const unsigned short* __restrict__ wbbuf,
                                               const unsigned short* __restrict__ tail,
                                               const unsigned short* __restrict__ pack,
                                               unsigned short* __restrict__ hpre,
                                               float* __restrict__ pbuf)
{
    __shared__ float lds[8 * 128 * 2];
    int wave = (blockIdx.x * 256 + threadIdx.x) >> 6;
    int lane = threadIdx.x & 63;
    int la = lane & 15, lb = lane >> 4;
    int row = wave * 16 + la;
    const unsigned short* fa_row = faT   + (size_t)row * C_ + lb * 8;
    const unsigned short* wb_row = wbbuf + (size_t)row * C_ + lb * 8;
    f32x4 acc[4] = {{0,0,0,0},{0,0,0,0},{0,0,0,0},{0,0,0,0}};

#pragma unroll
    for (int ks = 0; ks < 8; ks++) {
        s16x8 a = *(const s16x8*)(fa_row + ks * 32);
#pragma unroll
        for (int nt = 0; nt < 4; nt++)
            acc[nt] = __builtin_amdgcn_mfma_f32_16x16x32_bf16(a,
                *(const s16x8*)(pack + ((size_t)(ks * 4 + nt) * 64 + lane) * 8), acc[nt], 0, 0, 0);
    }
#pragma unroll
    for (int ks = 0; ks < 8; ks++) {
        s16x8 a = *(const s16x8*)(wb_row + ks * 32);
#pragma unroll
        for (int nt = 0; nt < 4; nt++)
            acc[nt] = __builtin_amdgcn_mfma_f32_16x16x32_bf16(a,
                *(const s16x8*)(pack + ((size_t)((ks + 8) * 4 + nt) * 64 + lane) * 8), acc[nt], 0, 0, 0);
    }
#pragma unroll
    for (int ks = 0; ks < 8; ks++) {
        u16x8 av = *(const u16x8*)(fa_row + ks * 32);
        u16x8 bv = *(const u16x8*)(wb_row + ks * 32);
        s16x8 a;
#pragma unroll
        for (int j = 0; j < 8; j++)
            a[j] = (short)f2bf(fabsf(bf2f(av[j]) - bf2f(bv[j])));
#pragma unroll
        for (int nt = 0; nt < 4; nt++)
            acc[nt] = __builtin_amdgcn_mfma_f32_16x16x32_bf16(a,
                *(const s16x8*)(pack + ((size_t)((ks + 16) * 4 + nt) * 64 + lane) * 8), acc[nt], 0, 0, 0);
    }
    {
        s16x8 a = *(const s16x8*)(tail + (size_t)row * 32 + lb * 8);
#pragma unroll
        for (int nt = 0; nt < 4; nt++)
            acc[nt] = __builtin_amdgcn_mfma_f32_16x16x32_bf16(a,
                *(const s16x8*)(pack + ((size_t)(24 * 4 + nt) * 64 + lane) * 8), acc[nt], 0, 0, 0);
    }

    int orow = wave * 16 + lb * 4;
#pragma unroll
    for (int nt = 0; nt < 4; nt++)
#pragma unroll
        for (int r = 0; r < 4; r++)
            hpre[(size_t)(orow + r) * HID + nt * 16 + la] = f2bf(acc[nt][r]);

    gn_epilogue(acc, lds, pbuf, blockIdx.x, la, lb, (threadIdx.x >> 6));
}

// ---------------- conv3x3 as MFMA implicit-im2col GEMM ----------------
__global__ __launch_bounds__(256) void k_conv3(const unsigned short* __restrict__ hin,
                                               const unsigned short* __restrict__ pack,
                                               unsigned short* __restrict__ hpre,
                                               float* __restrict__ pbuf)
{
    __shared__ float lds[8 * 128 * 2];
    int wave = (blockIdx.x * 256 + threadIdx.x) >> 6;
    int lane = threadIdx.x & 63;
    int la = lane & 15, lb = lane >> 4;
    int b = wave >> 10, y = (wave >> 3) & 127, xb = (wave & 7) * 16;
    int xx = xb + la;
    f32x4 acc[4] = {{0,0,0,0},{0,0,0,0},{0,0,0,0},{0,0,0,0}};
#pragma unroll
    for (int ks = 0; ks < K3STEPS; ks++) {
        int tap = ks >> 1;
        int yy = y + tap / 3 - 1;
        int xq = xx + tap % 3 - 1;
        s16x8 a = {0,0,0,0,0,0,0,0};
        if ((unsigned)yy < 128u && (unsigned)xq < 128u)
            a = *(const s16x8*)(hin + ((size_t)((b * 128 + yy) * 128 + xq)) * HID
                                + (ks & 1) * 32 + lb * 8);
#pragma unroll
        for (int nt = 0; nt < 4; nt++)
            acc[nt] = __builtin_amdgcn_mfma_f32_16x16x32_bf16(a,
                *(const s16x8*)(pack + ((size_t)(ks * 4 + nt) * 64 + lane) * 8), acc[nt], 0, 0, 0);
    }
    int orow = wave * 16 + lb * 4;
#pragma unroll
    for (int nt = 0; nt < 4; nt++)
#pragma unroll
        for (int r = 0; r < 4; r++)
            hpre[(size_t)(orow + r) * HID + nt * 16 + la] = f2bf(acc[nt][r]);

    gn_epilogue(acc, lds, pbuf, blockIdx.x, la, lb, (threadIdx.x >> 6));
}

// ---------------- GN fold + apply + exact GELU ----------------
__global__ __launch_bounds__(256) void k_gnapply(const unsigned short* __restrict__ hpre,
                                                 const float* __restrict__ gamma,
                                                 const float* __restrict__ beta,
                                                 const float* __restrict__ pbuf,
                                                 unsigned short* __restrict__ hn)
{
    int pix0 = blockIdx.x * 32;
    int b = pix0 >> 14;
    __shared__ float sm[16];
    {
        int g = threadIdx.x >> 5, i = threadIdx.x & 31;
        float s = 0.f, s2 = 0.f;
#pragma unroll
        for (int k = 0; k < 8; k++) {
            int bid = b * 256 + i + k * 32;
            s  += pbuf[(bid * 8 + g) * 2];
            s2 += pbuf[(bid * 8 + g) * 2 + 1];
        }
#pragma unroll
        for (int m = 1; m < 32; m <<= 1) { s += __shfl_xor(s, m); s2 += __shfl_xor(s2, m); }
        if (i == 0) {
            const float inv = 1.f / 131072.f;
            float mean = s * inv;
            float var = fmaxf(s2 * inv - mean * mean, 0.f);
            sm[g * 2] = mean;
            sm[g * 2 + 1] = rsqrtf(var + 1e-5f);
        }
    }
    __syncthreads();
    int t = blockIdx.x * 256 + threadIdx.x;
    int pix = t >> 3, g = t & 7;
    float mean = sm[g * 2], rstd = sm[g * 2 + 1];
    u16x8 v = *(const u16x8*)(hpre + (size_t)pix * HID + g * 8);
    u16x8 o;
#pragma unroll
    for (int i = 0; i < 8; i++) {
        int c = g * 8 + i;
        float xn = (bf2f(v[i]) - mean) * rstd * gamma[c] + beta[c];
        float ge = 0.5f * xn * (1.f + erff(xn * 0.70710678118654752f));
        o[i] = f2bf(ge);
    }
    *(u16x8*)(hn + (size_t)pix * HID + g * 8) = o;
}

// ---------------- delta/conf heads + epilogue (8 threads / pixel) ----------------
__global__ __launch_bounds__(256) void k_final(const unsigned short* __restrict__ hn,
                                               const float* __restrict__ cw,
                                               const float* __restrict__ confp,
                                               const float* __restrict__ dw,
                                               const float* __restrict__ db,
                                               const float* __restrict__ cwgt,
                                               const float* __restrict__ cb,
                                               float* __restrict__ out)
{
    __shared__ float wds[1154];
    __shared__ float wcs[577];
    int tid = threadIdx.x;
    for (int i = tid; i < 1152; i += 256) wds[i] = dw[i];
    for (int i = tid; i < 576; i += 256) wcs[i] = cwgt[i];
    if (tid == 0) { wds[1152] = db[0]; wds[1153] = db[1]; wcs[576] = cb[0]; }
    __syncthreads();

    int t = blockIdx.x * 256 + tid;
    int pix = t >> 3, part = t & 7;
    int b = pix >> 14, y = (pix >> 7) & 127, x = pix & 127;

    float d0 = 0.f, d1 = 0.f, c0 = 0.f;
#pragma unroll
    for (int ky = 0; ky < 3; ky++) {
        int yy = y + ky - 1;
        if ((unsigned)yy >= 128u) continue;
#pragma unroll
        for (int kx = 0; kx < 3; kx++) {
            int xq = x + kx - 1;
            if ((unsigned)xq >= 128u) continue;
            const unsigned short* hp = hn + (size_t)((b * 128 + yy) * 128 + xq) * HID + part * 8;
            int widx = ky * 3 + kx;
            u16x8 v = *(const u16x8*)hp;
#pragma unroll
            for (int i = 0; i < 8; i++) {
                float f = bf2f(v[i]);
                int c = part * 8 + i;
                d0 += f * wds[c * 9 + widx];
                d1 += f * wds[576 + c * 9 + widx];
                c0 += f * wcs[c * 9 + widx];
            }
        }
    }
#pragma unroll
    for (int m = 1; m < 8; m <<= 1) {
        d0 += __shfl_xor(d0, m);
        d1 += __shfl_xor(d1, m);
        c0 += __shfl_xor(c0, m);
    }
    if (part == 0) {
        d0 = tanhf(d0 + wds[1152]);
        d1 = tanhf(d1 + wds[1153]);
        c0 += wcs[576];

        float gx = clean15(cw[(size_t)pix * 2 + 0]);
        float gy = clean15(cw[(size_t)pix * 2 + 1]);
        float fwx = fminf(fmaxf(gx + d0 * 0.0625f, -1.5f), 1.5f);
        float fwy = fminf(fmaxf(gy + d1 * 0.0625f, -1.5f), 1.5f);

        float conf = clean01(confp[pix]);
        float p = fminf(fmaxf(conf, 1e-4f), 1.f - 1e-4f);
        float bl = logf(p) - log1pf(-p);
        float rl = bl + 0.5f * c0;
        float rc = fminf(fmaxf(1.f / (1.f + expf(-rl)), 0.f), 1.f);

        out[(size_t)pix * 2 + 0] = fwx;
        out[(size_t)pix * 2 + 1] = fwy;
        out[(size_t)NPIX * 2 + pix] = rc;
        out[(size_t)NPIX * 2 + NPIX + pix] = rl;
    }
}

// ---------------- launcher ----------------
extern "C" void kernel_launch(void* const* d_in, const int* in_sizes, int n_in,
                              void* d_out, int out_size, void* d_ws, size_t ws_size,
                              hipStream_t stream)
{
    const float* feat_A = (const float*)d_in[0];
    const float* feat_B = (const float*)d_in[1];
    const float* cw     = (const float*)d_in[2];
    const float* conf   = (const float*)d_in[3];
    const float* w1     = (const float*)d_in[4];
    const float* g1     = (const float*)d_in[5];
    const float* b1     = (const float*)d_in[6];
    const float* w2     = (const float*)d_in[7];
    const float* g2     = (const float*)d_in[8];
    const float* b2     = (const float*)d_in[9];
    const float* w3     = (const float*)d_in[10];
    const float* g3     = (const float*)d_in[11];
    const float* b3     = (const float*)d_in[12];
    const float* dw     = (const float*)d_in[13];
    const float* db     = (const float*)d_in[14];
    const float* cwgt   = (const float*)d_in[15];
    const float* cb     = (const float*)d_in[16];
    float* out = (float*)d_out;

    char* w = (char*)d_ws;
    size_t o = 0;
    unsigned short* faT  = (unsigned short*)(w + o); o += (size_t)NPIX * C_ * 2;     // 16 MB
    unsigned short* fbT  = (unsigned short*)(w + o); o += (size_t)NPIX * C_ * 2;     // 16 MB
    unsigned short* wbb  = (unsigned short*)(w + o); o += (size_t)NPIX * C_ * 2;     // 16 MB
    unsigned short* tail = (unsigned short*)(w + o); o += (size_t)NPIX * 32 * 2;     // 2 MB
    unsigned short* hpre = (unsigned short*)(w + o); o += (size_t)NPIX * HID * 2;    // 4 MB
    unsigned short* hnA  = (unsigned short*)(w + o); o += (size_t)NPIX * HID * 2;
    unsigned short* hnB  = (unsigned short*)(w + o); o += (size_t)NPIX * HID * 2;
    unsigned short* p1   = (unsigned short*)(w + o); o += (size_t)K1STEPS * 4 * 64 * 8 * 2;
    unsigned short* p2   = (unsigned short*)(w + o); o += (size_t)K3STEPS * 4 * 64 * 8 * 2;
    unsigned short* p3   = (unsigned short*)(w + o); o += (size_t)K3STEPS * 4 * 64 * 8 * 2;
    float* pbuf = (float*)(w + o);    // 512 * 8 * 2 floats = 32 KB

    k_transpose<<<dim3(PIX_PER / 32, C_ / 32, 4), 256, 0, stream>>>(feat_A, feat_B, faT, fbT);
    k_pack<<<61, 256, 0, stream>>>(w1, w2, w3, p1, p2, p3);
    k_sample<<<NPIX / 4, 256, 0, stream>>>(cw, conf, faT, fbT, wbb, tail);

    k_gemm1<<<(NPIX / 16) / 4, 256, 0, stream>>>(faT, wbb, tail, p1, hpre, pbuf);
    k_gnapply<<<NPIX / 32, 256, 0, stream>>>(hpre, g1, b1, pbuf, hnA);

    k_conv3<<<(NPIX / 16) / 4, 256, 0, stream>>>(hnA, p2, hpre, pbuf);
    k_gnapply<<<NPIX / 32, 256, 0, stream>>>(hpre, g2, b2, pbuf, hnB);

    k_conv3<<<(NPIX / 16) / 4, 256, 0, stream>>>(hnB, p3, hpre, pbuf);
    k_gnapply<<<NPIX / 32, 256, 0, stream>>>(hpre, g3, b3, pbuf, hnA);

    k_final<<<NPIX * 8 / 256, 256, 0, stream>>>(hnA, cw, conf, dw, db, cwgt, cb, out);
}

// Round 4
// 138.879 us; speedup vs baseline: 1.8264x; 1.0920x over previous
//
#include <hip/hip_runtime.h>
#include <hip/hip_bf16.h>
#include <math.h>

#define B_ 2
#define H_ 128
#define W_ 128
#define C_ 256
#define HID 64
#define PIX_PER (H_*W_)          // 16384
#define NPIX (B_*PIX_PER)        // 32768
#define K1STEPS 25               // 800 / 32 (fa 0-7, wb 8-15, diff 16-23, tail 24)
#define K3STEPS 18               // 576 / 32

using f32x2 = __attribute__((ext_vector_type(2))) float;
using f32x4 = __attribute__((ext_vector_type(4))) float;
using s16x8 = __attribute__((ext_vector_type(8))) short;
using u16x2 = __attribute__((ext_vector_type(2))) unsigned short;
using u16x4 = __attribute__((ext_vector_type(4))) unsigned short;
using u16x8 = __attribute__((ext_vector_type(8))) unsigned short;
using u32x4 = __attribute__((ext_vector_type(4))) unsigned int;

__device__ __forceinline__ float bf2f(unsigned short u) {
    return __uint_as_float(((unsigned)u) << 16);
}
__device__ __forceinline__ unsigned short f2bf(float f) {
    unsigned u = __float_as_uint(f);
    u += 0x7FFFu + ((u >> 16) & 1u);
    return (unsigned short)(u >> 16);
}
__device__ __forceinline__ float clean15(float v) {
    if (v != v) v = 0.f;
    return fminf(fmaxf(v, -1.5f), 1.5f);
}
__device__ __forceinline__ float clean01(float v) {
    if (v != v) v = 0.f;
    return fminf(fmaxf(v, 0.f), 1.f);
}
// 8 packed bf16 (as 4 dwords) -> 4 float2
__device__ __forceinline__ void cvt8(u32x4 v, f32x2* o) {
#pragma unroll
    for (int p = 0; p < 4; p++) {
        f32x2 t;
        t.x = __uint_as_float(v[p] << 16);
        t.y = __uint_as_float(v[p] & 0xffff0000u);
        o[p] = t;
    }
}

// ---------------- transpose NCHW -> NHWC bf16 with nan cleanup ----------------
__global__ __launch_bounds__(256) void k_transpose(const float* __restrict__ A,
                                                   const float* __restrict__ Bm,
                                                   unsigned short* __restrict__ faT,
                                                   unsigned short* __restrict__ fbT)
{
    __shared__ float tile[32][33];
    int hw0 = blockIdx.x * 32;
    int c0  = blockIdx.y * 32;
    int z   = blockIdx.z;            // b*2 + which
    int b   = z >> 1;
    const float* src = (z & 1) ? Bm : A;
    unsigned short* dst = (z & 1) ? fbT : faT;
    int tx = threadIdx.x & 31, ty = threadIdx.x >> 5;   // 32 x 8
    const float* s = src + ((size_t)b * C_ + c0) * (size_t)PIX_PER + hw0;
#pragma unroll
    for (int i = 0; i < 32; i += 8) {
        float v = s[(size_t)(ty + i) * PIX_PER + tx];
        if (!isfinite(v)) v = 0.f;
        tile[ty + i][tx] = v;
    }
    __syncthreads();
    unsigned short* d = dst + ((size_t)b * PIX_PER + hw0) * C_ + c0;
#pragma unroll
    for (int i = 0; i < 32; i += 8) {
        int hwl = ty + i;
        u16x2 o;
        o[0] = f2bf(tile[2 * tx][hwl]);
        o[1] = f2bf(tile[2 * tx + 1][hwl]);
        *(u16x2*)(d + (size_t)hwl * C_ + 2 * tx) = o;
    }
}

// ---------------- weight packing into MFMA B-fragment order ----------------
__global__ __launch_bounds__(256) void k_pack(const float* __restrict__ w1,
                                              const float* __restrict__ w2,
                                              const float* __restrict__ w3,
                                              unsigned short* __restrict__ p1,
                                              unsigned short* __restrict__ p2,
                                              unsigned short* __restrict__ p3)
{
    int t = blockIdx.x * 256 + threadIdx.x;
    if (t < 6400) {                                   // enc1: 25 ksteps
        int lane = t & 63, nt = (t >> 6) & 3, ks = t >> 8;
        int n = nt * 16 + (lane & 15);
        int kb = ks * 32 + 8 * (lane >> 4);
#pragma unroll
        for (int j = 0; j < 8; j++) {
            int k = kb + j;
            p1[(size_t)t * 8 + j] = (k < 780) ? f2bf(w1[(size_t)n * 780 + k]) : (unsigned short)0;
        }
    } else if (t < 6400 + 2 * 4608) {                 // enc2/enc3: 18 ksteps each
        int which = (t - 6400) / 4608;
        int idx = (t - 6400) % 4608;
        const float* w = which ? w3 : w2;
        unsigned short* p = which ? p3 : p2;
        int lane = idx & 63, nt = (idx >> 6) & 3, ks = idx >> 8;
        int n = nt * 16 + (lane & 15);
        int tap = ks >> 1;
        int ky = tap / 3, kx = tap % 3;
#pragma unroll
        for (int j = 0; j < 8; j++) {
            int c = (ks & 1) * 32 + 8 * (lane >> 4) + j;
            p[(size_t)idx * 8 + j] = f2bf(w[(((size_t)n * 64 + c) * 3 + ky) * 3 + kx]);
        }
    }
}

// -------- sampling + correlation: 2 pixels/wave, 32 lanes/pixel, 8 ch/lane --------
// Identity (validated r1-r3): the 9 offsets are exact +-1 px shifts -> all 36
// bilinear taps live in one 4x4 neighborhood sharing one (wx,wy); border clamps
// collapse taps so no weight fixup needed. Row decomposition: rx=lerp_x, then
// A=fa.rx, P=|rx|^2, Q=rx_r.rx_{r+1}; per-lane combine with wave-uniform wy
// weights; 5-step xor reduce within each 32-lane half (2 px reduced at once).
// float2 math throughout -> v_pk_fma_f32.
__global__ __launch_bounds__(256) void k_sample(const float* __restrict__ cw,
                                                const float* __restrict__ confp,
                                                const unsigned short* __restrict__ faT,
                                                const unsigned short* __restrict__ fbT,
                                                unsigned short* __restrict__ wbbuf,
                                                unsigned short* __restrict__ tail)
{
    int lane = threadIdx.x & 63;
    int wave = (blockIdx.x * 256 + threadIdx.x) >> 6;
    int sub = lane & 31;
    int wid = wave * 2 + (lane >> 5);
    int b = wid >> 14, y = (wid >> 7) & 127, x = wid & 127;

    float gx = clean15(cw[(size_t)wid * 2 + 0]);
    float gy = clean15(cw[(size_t)wid * 2 + 1]);

    float pxu = (gx + 1.f) * 64.f - 0.5f;
    float pyu = (gy + 1.f) * 64.f - 0.5f;
    float x0f = floorf(pxu), y0f = floorf(pyu);
    float wx = pxu - x0f, wy = pyu - y0f;
    int x0 = (int)x0f, y0 = (int)y0f;
    int co[4], ro[4];
#pragma unroll
    for (int k = 0; k < 4; k++) {
        co[k] = min(max(x0 - 1 + k, 0), 127) << 8;     // cx * C_
        ro[k] = min(max(y0 - 1 + k, 0), 127) << 15;    // cy * 128 * C_
    }
    const unsigned short* fbB = fbT + ((size_t)b << 22) + sub * 8;
    const f32x2 wx2 = {wx, wx};

    f32x2 fav[4];
    cvt8(*(const u32x4*)(faT + (size_t)wid * C_ + sub * 8), fav);
    f32x2 fa2v = fav[0]*fav[0] + fav[1]*fav[1] + fav[2]*fav[2] + fav[3]*fav[3];
    float fa2 = fa2v.x + fa2v.y;

    float A[4][3], P[4][3], Q[3][3];
    f32x2 rxp[3][4];
    f32x2 wbv[4];

#pragma unroll
    for (int r = 0; r < 4; r++) {
        u32x4 tp[4];
#pragma unroll
        for (int k = 0; k < 4; k++)
            tp[k] = *(const u32x4*)(fbB + ro[r] + co[k]);
        f32x2 e0[4], e1[4];
        cvt8(tp[0], e0);
#pragma unroll
        for (int dx = 0; dx < 3; dx++) {
            cvt8(tp[dx + 1], e1);
            f32x2 rx[4];
            f32x2 a = {0.f, 0.f}, p = {0.f, 0.f};
#pragma unroll
            for (int i = 0; i < 4; i++) {
                rx[i] = e0[i] + wx2 * (e1[i] - e0[i]);
                a += fav[i] * rx[i];
                p += rx[i] * rx[i];
            }
            A[r][dx] = a.x + a.y;
            P[r][dx] = p.x + p.y;
            if (r > 0) {
                f32x2 q = rxp[dx][0]*rx[0] + rxp[dx][1]*rx[1]
                        + rxp[dx][2]*rx[2] + rxp[dx][3]*rx[3];
                Q[r - 1][dx] = q.x + q.y;
            }
            if (dx == 1) {
                if (r == 1) {
#pragma unroll
                    for (int i = 0; i < 4; i++) wbv[i] = rx[i];
                }
                if (r == 2) {
                    f32x2 wy2 = {wy, wy};
#pragma unroll
                    for (int i = 0; i < 4; i++) wbv[i] += wy2 * (rx[i] - wbv[i]);
                }
            }
#pragma unroll
            for (int i = 0; i < 4; i++) { rxp[dx][i] = rx[i]; e0[i] = e1[i]; }
        }
    }

    u16x8 wbo;
#pragma unroll
    for (int i = 0; i < 4; i++) {
        wbo[2 * i]     = f2bf(wbv[i].x);
        wbo[2 * i + 1] = f2bf(wbv[i].y);
    }
    *(u16x8*)(wbbuf + (size_t)wid * C_ + sub * 8) = wbo;

    float red[19];
    float u0 = (1.f - wy) * (1.f - wy), u1 = 2.f * wy * (1.f - wy), u2 = wy * wy;
#pragma unroll
    for (int j = 0; j < 9; j++) {
        int dy = j / 3, dx = j % 3;
        red[j]     = A[dy][dx] + wy * (A[dy + 1][dx] - A[dy][dx]);
        red[9 + j] = u0 * P[dy][dx] + u1 * Q[dy][dx] + u2 * P[dy + 1][dx];
    }
    red[18] = fa2;
#pragma unroll
    for (int m = 1; m < 32; m <<= 1)
#pragma unroll
        for (int j = 0; j < 19; j++)
            red[j] += __shfl_xor(red[j], m);

    if (sub == 0) {
        float conf = clean01(confp[wid]);
        float inv_na = rsqrtf(fmaxf(red[18], 1e-24f));
        float srcx = ((float)x + 0.5f) * 0.015625f - 1.f;
        float srcy = ((float)y + 0.5f) * 0.015625f - 1.f;
        u16x8 t0, t1, tz;
        t0[0] = f2bf(gx - srcx);
        t0[1] = f2bf(gy - srcy);
        t0[2] = f2bf(conf);
#pragma unroll
        for (int j = 0; j < 5; j++)
            t0[3 + j] = f2bf(red[j] * inv_na * rsqrtf(fmaxf(red[9 + j], 1e-24f)));
#pragma unroll
        for (int j = 0; j < 4; j++)
            t1[j] = f2bf(red[5 + j] * inv_na * rsqrtf(fmaxf(red[14 + j], 1e-24f)));
#pragma unroll
        for (int j = 4; j < 8; j++) t1[j] = 0;
#pragma unroll
        for (int j = 0; j < 8; j++) tz[j] = 0;
        unsigned short* tr = tail + (size_t)wid * 32;
        *(u16x8*)(tr)      = t0;
        *(u16x8*)(tr + 8)  = t1;
        *(u16x8*)(tr + 16) = tz;
        *(u16x8*)(tr + 24) = tz;
    }
}

// ---- GN partial-stats epilogue shared by gemm1/conv3 (per-block partials) ----
__device__ __forceinline__ void gn_epilogue(const f32x4 acc[4], float* lds,
                                            float* __restrict__ pbuf, int bid,
                                            int la, int lb, int wv)
{
    int d = la >> 3;
    int slot = wv * 32 + lb * 8 + (la & 7);
#pragma unroll
    for (int nt = 0; nt < 4; nt++) {
        float s  = acc[nt][0] + acc[nt][1] + acc[nt][2] + acc[nt][3];
        float s2 = acc[nt][0] * acc[nt][0] + acc[nt][1] * acc[nt][1]
                 + acc[nt][2] * acc[nt][2] + acc[nt][3] * acc[nt][3];
        int g = nt * 2 + d;
        lds[(g * 128 + slot) * 2 + 0] = s;
        lds[(g * 128 + slot) * 2 + 1] = s2;
    }
    __syncthreads();
    int tid = threadIdx.x;
    int g = tid >> 5, i = tid & 31;
    float s  = lds[(g * 128 + i) * 2]     + lds[(g * 128 + i + 32) * 2]
             + lds[(g * 128 + i + 64) * 2] + lds[(g * 128 + i + 96) * 2];
    float s2 = lds[(g * 128 + i) * 2 + 1]     + lds[(g * 128 + i + 32) * 2 + 1]
             + lds[(g * 128 + i + 64) * 2 + 1] + lds[(g * 128 + i + 96) * 2 + 1];
#pragma unroll
    for (int m = 1; m < 32; m <<= 1) { s += __shfl_xor(s, m); s2 += __shfl_xor(s2, m); }
    if (i == 0) {
        pbuf[(bid * 8 + g) * 2]     = s;
        pbuf[(bid * 8 + g) * 2 + 1] = s2;
    }
}

// ---------------- conv1x1 as MFMA GEMM, A assembled on the fly ----------------
__global__ __launch_bounds__(256) void k_gemm1(const unsigned short* __restrict__ faT,
                                               const unsigned short* __restrict__ wbbuf,
                                               const unsigned short* __restrict__ tail,
                                               const unsigned short* __restrict__ pack,
                                               unsigned short* __restrict__ hpre,
                                               float* __restrict__ pbuf)
{
    __shared__ float lds[8 * 128 * 2];
    int wave = (blockIdx.x * 256 + threadIdx.x) >> 6;
    int lane = threadIdx.x & 63;
    int la = lane & 15, lb = lane >> 4;
    int row = wave * 16 + la;
    const unsigned short* fa_row = faT   + (size_t)row * C_ + lb * 8;
    const unsigned short* wb_row = wbbuf + (size_t)row * C_ + lb * 8;
    f32x4 acc[4] = {{0,0,0,0},{0,0,0,0},{0,0,0,0},{0,0,0,0}};

#pragma unroll
    for (int ks = 0; ks < 8; ks++) {
        s16x8 a = *(const s16x8*)(fa_row + ks * 32);
#pragma unroll
        for (int nt = 0; nt < 4; nt++)
            acc[nt] = __builtin_amdgcn_mfma_f32_16x16x32_bf16(a,
                *(const s16x8*)(pack + ((size_t)(ks * 4 + nt) * 64 + lane) * 8), acc[nt], 0, 0, 0);
    }
#pragma unroll
    for (int ks = 0; ks < 8; ks++) {
        s16x8 a = *(const s16x8*)(wb_row + ks * 32);
#pragma unroll
        for (int nt = 0; nt < 4; nt++)
            acc[nt] = __builtin_amdgcn_mfma_f32_16x16x32_bf16(a,
                *(const s16x8*)(pack + ((size_t)((ks + 8) * 4 + nt) * 64 + lane) * 8), acc[nt], 0, 0, 0);
    }
#pragma unroll
    for (int ks = 0; ks < 8; ks++) {
        u16x8 av = *(const u16x8*)(fa_row + ks * 32);
        u16x8 bv = *(const u16x8*)(wb_row + ks * 32);
        s16x8 a;
#pragma unroll
        for (int j = 0; j < 8; j++)
            a[j] = (short)f2bf(fabsf(bf2f(av[j]) - bf2f(bv[j])));
#pragma unroll
        for (int nt = 0; nt < 4; nt++)
            acc[nt] = __builtin_amdgcn_mfma_f32_16x16x32_bf16(a,
                *(const s16x8*)(pack + ((size_t)((ks + 16) * 4 + nt) * 64 + lane) * 8), acc[nt], 0, 0, 0);
    }
    {
        s16x8 a = *(const s16x8*)(tail + (size_t)row * 32 + lb * 8);
#pragma unroll
        for (int nt = 0; nt < 4; nt++)
            acc[nt] = __builtin_amdgcn_mfma_f32_16x16x32_bf16(a,
                *(const s16x8*)(pack + ((size_t)(24 * 4 + nt) * 64 + lane) * 8), acc[nt], 0, 0, 0);
    }

    int orow = wave * 16 + lb * 4;
#pragma unroll
    for (int nt = 0; nt < 4; nt++)
#pragma unroll
        for (int r = 0; r < 4; r++)
            hpre[(size_t)(orow + r) * HID + nt * 16 + la] = f2bf(acc[nt][r]);

    gn_epilogue(acc, lds, pbuf, blockIdx.x, la, lb, (threadIdx.x >> 6));
}

// ---------------- conv3x3 as MFMA implicit-im2col GEMM ----------------
__global__ __launch_bounds__(256) void k_conv3(const unsigned short* __restrict__ hin,
                                               const unsigned short* __restrict__ pack,
                                               unsigned short* __restrict__ hpre,
                                               float* __restrict__ pbuf)
{
    __shared__ float lds[8 * 128 * 2];
    int wave = (blockIdx.x * 256 + threadIdx.x) >> 6;
    int lane = threadIdx.x & 63;
    int la = lane & 15, lb = lane >> 4;
    int b = wave >> 10, y = (wave >> 3) & 127, xb = (wave & 7) * 16;
    int xx = xb + la;
    f32x4 acc[4] = {{0,0,0,0},{0,0,0,0},{0,0,0,0},{0,0,0,0}};
#pragma unroll
    for (int ks = 0; ks < K3STEPS; ks++) {
        int tap = ks >> 1;
        int yy = y + tap / 3 - 1;
        int xq = xx + tap % 3 - 1;
        s16x8 a = {0,0,0,0,0,0,0,0};
        if ((unsigned)yy < 128u && (unsigned)xq < 128u)
            a = *(const s16x8*)(hin + ((size_t)((b * 128 + yy) * 128 + xq)) * HID
                                + (ks & 1) * 32 + lb * 8);
#pragma unroll
        for (int nt = 0; nt < 4; nt++)
            acc[nt] = __builtin_amdgcn_mfma_f32_16x16x32_bf16(a,
                *(const s16x8*)(pack + ((size_t)(ks * 4 + nt) * 64 + lane) * 8), acc[nt], 0, 0, 0);
    }
    int orow = wave * 16 + lb * 4;
#pragma unroll
    for (int nt = 0; nt < 4; nt++)
#pragma unroll
        for (int r = 0; r < 4; r++)
            hpre[(size_t)(orow + r) * HID + nt * 16 + la] = f2bf(acc[nt][r]);

    gn_epilogue(acc, lds, pbuf, blockIdx.x, la, lb, (threadIdx.x >> 6));
}

// ---------------- GN fold + apply + exact GELU ----------------
__global__ __launch_bounds__(256) void k_gnapply(const unsigned short* __restrict__ hpre,
                                                 const float* __restrict__ gamma,
                                                 const float* __restrict__ beta,
                                                 const float* __restrict__ pbuf,
                                                 unsigned short* __restrict__ hn)
{
    int pix0 = blockIdx.x * 32;
    int b = pix0 >> 14;
    __shared__ float sm[16];
    {
        int g = threadIdx.x >> 5, i = threadIdx.x & 31;
        float s = 0.f, s2 = 0.f;
#pragma unroll
        for (int k = 0; k < 8; k++) {
            int bid = b * 256 + i + k * 32;
            s  += pbuf[(bid * 8 + g) * 2];
            s2 += pbuf[(bid * 8 + g) * 2 + 1];
        }
#pragma unroll
        for (int m = 1; m < 32; m <<= 1) { s += __shfl_xor(s, m); s2 += __shfl_xor(s2, m); }
        if (i == 0) {
            const float inv = 1.f / 131072.f;
            float mean = s * inv;
            float var = fmaxf(s2 * inv - mean * mean, 0.f);
            sm[g * 2] = mean;
            sm[g * 2 + 1] = rsqrtf(var + 1e-5f);
        }
    }
    __syncthreads();
    int t = blockIdx.x * 256 + threadIdx.x;
    int pix = t >> 3, g = t & 7;
    float mean = sm[g * 2], rstd = sm[g * 2 + 1];
    u16x8 v = *(const u16x8*)(hpre + (size_t)pix * HID + g * 8);
    u16x8 o;
#pragma unroll
    for (int i = 0; i < 8; i++) {
        int c = g * 8 + i;
        float xn = (bf2f(v[i]) - mean) * rstd * gamma[c] + beta[c];
        float ge = 0.5f * xn * (1.f + erff(xn * 0.70710678118654752f));
        o[i] = f2bf(ge);
    }
    *(u16x8*)(hn + (size_t)pix * HID + g * 8) = o;
}

// ---------------- delta/conf heads + epilogue (8 threads / pixel) ----------------
__global__ __launch_bounds__(256) void k_final(const unsigned short* __restrict__ hn,
                                               const float* __restrict__ cw,
                                               const float* __restrict__ confp,
                                               const float* __restrict__ dw,
                                               const float* __restrict__ db,
                                               const float* __restrict__ cwgt,
                                               const float* __restrict__ cb,
                                               float* __restrict__ out)
{
    __shared__ float wds[1154];
    __shared__ float wcs[577];
    int tid = threadIdx.x;
    for (int i = tid; i < 1152; i += 256) wds[i] = dw[i];
    for (int i = tid; i < 576; i += 256) wcs[i] = cwgt[i];
    if (tid == 0) { wds[1152] = db[0]; wds[1153] = db[1]; wcs[576] = cb[0]; }
    __syncthreads();

    int t = blockIdx.x * 256 + tid;
    int pix = t >> 3, part = t & 7;
    int b = pix >> 14, y = (pix >> 7) & 127, x = pix & 127;

    float d0 = 0.f, d1 = 0.f, c0 = 0.f;
#pragma unroll
    for (int ky = 0; ky < 3; ky++) {
        int yy = y + ky - 1;
        if ((unsigned)yy >= 128u) continue;
#pragma unroll
        for (int kx = 0; kx < 3; kx++) {
            int xq = x + kx - 1;
            if ((unsigned)xq >= 128u) continue;
            const unsigned short* hp = hn + (size_t)((b * 128 + yy) * 128 + xq) * HID + part * 8;
            int widx = ky * 3 + kx;
            u16x8 v = *(const u16x8*)hp;
#pragma unroll
            for (int i = 0; i < 8; i++) {
                float f = bf2f(v[i]);
                int c = part * 8 + i;
                d0 += f * wds[c * 9 + widx];
                d1 += f * wds[576 + c * 9 + widx];
                c0 += f * wcs[c * 9 + widx];
            }
        }
    }
#pragma unroll
    for (int m = 1; m < 8; m <<= 1) {
        d0 += __shfl_xor(d0, m);
        d1 += __shfl_xor(d1, m);
        c0 += __shfl_xor(c0, m);
    }
    if (part == 0) {
        d0 = tanhf(d0 + wds[1152]);
        d1 = tanhf(d1 + wds[1153]);
        c0 += wcs[576];

        float gx = clean15(cw[(size_t)pix * 2 + 0]);
        float gy = clean15(cw[(size_t)pix * 2 + 1]);
        float fwx = fminf(fmaxf(gx + d0 * 0.0625f, -1.5f), 1.5f);
        float fwy = fminf(fmaxf(gy + d1 * 0.0625f, -1.5f), 1.5f);

        float conf = clean01(confp[pix]);
        float p = fminf(fmaxf(conf, 1e-4f), 1.f - 1e-4f);
        float bl = logf(p) - log1pf(-p);
        float rl = bl + 0.5f * c0;
        float rc = fminf(fmaxf(1.f / (1.f + expf(-rl)), 0.f), 1.f);

        out[(size_t)pix * 2 + 0] = fwx;
        out[(size_t)pix * 2 + 1] = fwy;
        out[(size_t)NPIX * 2 + pix] = rc;
        out[(size_t)NPIX * 2 + NPIX + pix] = rl;
    }
}

// ---------------- launcher ----------------
extern "C" void kernel_launch(void* const* d_in, const int* in_sizes, int n_in,
                              void* d_out, int out_size, void* d_ws, size_t ws_size,
                              hipStream_t stream)
{
    const float* feat_A = (const float*)d_in[0];
    const float* feat_B = (const float*)d_in[1];
    const float* cw     = (const float*)d_in[2];
    const float* conf   = (const float*)d_in[3];
    const float* w1     = (const float*)d_in[4];
    const float* g1     = (const float*)d_in[5];
    const float* b1     = (const float*)d_in[6];
    const float* w2     = (const float*)d_in[7];
    const float* g2     = (const float*)d_in[8];
    const float* b2     = (const float*)d_in[9];
    const float* w3     = (const float*)d_in[10];
    const float* g3     = (const float*)d_in[11];
    const float* b3     = (const float*)d_in[12];
    const float* dw     = (const float*)d_in[13];
    const float* db     = (const float*)d_in[14];
    const float* cwgt   = (const float*)d_in[15];
    const float* cb     = (const float*)d_in[16];
    float* out = (float*)d_out;

    char* w = (char*)d_ws;
    size_t o = 0;
    unsigned short* faT  = (unsigned short*)(w + o); o += (size_t)NPIX * C_ * 2;     // 16 MB
    unsigned short* fbT  = (unsigned short*)(w + o); o += (size_t)NPIX * C_ * 2;     // 16 MB
    unsigned short* wbb  = (unsigned short*)(w + o); o += (size_t)NPIX * C_ * 2;     // 16 MB
    unsigned short* tail = (unsigned short*)(w + o); o += (size_t)NPIX * 32 * 2;     // 2 MB
    unsigned short* hpre = (unsigned short*)(w + o); o += (size_t)NPIX * HID * 2;    // 4 MB
    unsigned short* hnA  = (unsigned short*)(w + o); o += (size_t)NPIX * HID * 2;
    unsigned short* hnB  = (unsigned short*)(w + o); o += (size_t)NPIX * HID * 2;
    unsigned short* p1   = (unsigned short*)(w + o); o += (size_t)K1STEPS * 4 * 64 * 8 * 2;
    unsigned short* p2   = (unsigned short*)(w + o); o += (size_t)K3STEPS * 4 * 64 * 8 * 2;
    unsigned short* p3   = (unsigned short*)(w + o); o += (size_t)K3STEPS * 4 * 64 * 8 * 2;
    float* pbuf = (float*)(w + o);    // 512 * 8 * 2 floats = 32 KB

    k_transpose<<<dim3(PIX_PER / 32, C_ / 32, 4), 256, 0, stream>>>(feat_A, feat_B, faT, fbT);
    k_pack<<<61, 256, 0, stream>>>(w1, w2, w3, p1, p2, p3);
    k_sample<<<NPIX / 8, 256, 0, stream>>>(cw, conf, faT, fbT, wbb, tail);

    k_gemm1<<<(NPIX / 16) / 4, 256, 0, stream>>>(faT, wbb, tail, p1, hpre, pbuf);
    k_gnapply<<<NPIX / 32, 256, 0, stream>>>(hpre, g1, b1, pbuf, hnA);

    k_conv3<<<(NPIX / 16) / 4, 256, 0, stream>>>(hnA, p2, hpre, pbuf);
    k_gnapply<<<NPIX / 32, 256, 0, stream>>>(hpre, g2, b2, pbuf, hnB);

    k_conv3<<<(NPIX / 16) / 4, 256, 0, stream>>>(hnB, p3, hpre, pbuf);
    k_gnapply<<<NPIX / 32, 256, 0, stream>>>(hpre, g3, b3, pbuf, hnA);

    k_final<<<NPIX * 8 / 256, 256, 0, stream>>>(hnA, cw, conf, dw, db, cwgt, cb, out);
}